// Round 9
// baseline (1368.522 us; speedup 1.0000x reference)
//
#include <hip/hip_runtime.h>

typedef __bf16 bf16_t;
typedef __bf16 bf16x8 __attribute__((ext_vector_type(8)));
typedef float f32x4 __attribute__((ext_vector_type(4)));
typedef unsigned short u16;

#define DEV static __device__ __forceinline__

DEV float bf2f(u16 u) { __bf16 h = __builtin_bit_cast(__bf16, u); return (float)h; }
DEV u16 f2bf(float f) { __bf16 h = (__bf16)f; return __builtin_bit_cast(u16, h); }

// async global->LDS, 16B per lane; lds base must be wave-uniform.
DEV void gll16(bf16_t* lds, const bf16_t* g) {
    __builtin_amdgcn_global_load_lds(
        (const __attribute__((address_space(1))) void*)g,
        (__attribute__((address_space(3))) void*)lds, 16, 0, 0);
}

#define WAITV(N) asm volatile("s_waitcnt vmcnt(" #N ")" ::: "memory")

// ---------------------------------------------------------------------------
// 256x256-tile GEMM, 8 waves (2M x 4N), BK=64, double-buffered 128KiB LDS.
// Deep pipeline: tile t+2 staged IN FULL at the mid-barrier (buf[cur] is
// fully consumed there); end-of-iter WAITV(8) waits only for tile t+1, which
// was issued 1.5 iterations (~2 K-tiles) earlier -> full HBM latency cover.
// vmcnt never 0 in steady state; 2 barriers per K-tile.
// EPI: 0 = bf16 out (+f32 bias if non-null), 1 = bf16 out + bias + relu
// ---------------------------------------------------------------------------
template <int EPI>
__global__ __launch_bounds__(512, 1)
void gemm8p(const bf16_t* __restrict__ A, int lda,
            const bf16_t* __restrict__ Bt, int ldb,
            bf16_t* __restrict__ C, int ldc,
            const float* __restrict__ bias, int K,
            long kadv, long cadv)
{
    __shared__ bf16_t Asm[2 * 2 * 8192];   // [buf][half][128*64]
    __shared__ bf16_t Bsm[2 * 2 * 8192];
    const int tid = threadIdx.x, w = tid >> 6, l = tid & 63;
    const int z = blockIdx.z;
    A  += (size_t)z * kadv;
    Bt += (size_t)z * kadv;
    C  += (size_t)z * cadv;

    const int gx = gridDim.x;
    int lin = blockIdx.y * gx + blockIdx.x;
    const int nlin = gx * gridDim.y;
    lin = (lin & 7) * (nlin >> 3) + (lin >> 3);
    const size_t row0 = (size_t)(lin / gx) * 256;
    const size_t col0 = (size_t)(lin % gx) * 256;

    const int wr = w >> 2, wc = w & 3;
    const int bh = wc >> 1;
    const int browoff = (wc & 1) * 64;
    const int fr = l & 15, q = l >> 4, sw = l & 7;

    const int srow = w * 8 + (l >> 3);
    const int sslot8 = ((l & 7) ^ ((l >> 3) & 7)) * 8;
    const bf16_t* AgH0 = A  + (row0 + srow) * (size_t)lda + sslot8;
    const bf16_t* BgH0 = Bt + (col0 + srow) * (size_t)ldb + sslot8;
    const size_t a128 = (size_t)128 * lda, b128 = (size_t)128 * ldb;
    const size_t a64  = (size_t)64 * lda,  b64  = (size_t)64 * ldb;
    const int wlds = w * 512;

// stage ALL 4 pairs (8 loads) of K-tile tt into buffer buf
#define STAGE_TILE(buf, tt)                                                    \
    do {                                                                       \
        const int koff = (tt) * 64;                                            \
        gll16(Asm + ((buf)*2+0)*8192 + wlds,        AgH0 + koff);              \
        gll16(Asm + ((buf)*2+0)*8192 + 4096 + wlds, AgH0 + koff + a64);        \
        gll16(Asm + ((buf)*2+1)*8192 + wlds,        AgH0 + a128 + koff);       \
        gll16(Asm + ((buf)*2+1)*8192 + 4096 + wlds, AgH0 + a128 + koff + a64); \
        gll16(Bsm + ((buf)*2+0)*8192 + wlds,        BgH0 + koff);              \
        gll16(Bsm + ((buf)*2+0)*8192 + 4096 + wlds, BgH0 + koff + b64);        \
        gll16(Bsm + ((buf)*2+1)*8192 + wlds,        BgH0 + b128 + koff);       \
        gll16(Bsm + ((buf)*2+1)*8192 + 4096 + wlds, BgH0 + b128 + koff + b64); \
    } while (0)

    f32x4 acc[8][4] = {};
    const int NT = K >> 6;

    STAGE_TILE(0, 0);
    if (NT > 1) { STAGE_TILE(1, 1); WAITV(8); } else { WAITV(0); }
    __builtin_amdgcn_sched_barrier(0);
    __builtin_amdgcn_s_barrier();

    for (int t = 0; t < NT; ++t) {
        const int cur = t & 1;
        const bool hasN1 = (t + 1 < NT), hasN2 = (t + 2 < NT);
        const bf16_t* Ab = Asm + (cur * 2 + wr) * 8192;
        const bf16_t* Bb = Bsm + (cur * 2 + bh) * 8192;

        // region 1: read A(mi0-3) + B(all); 32 MFMA
        bf16x8 aR[4][2], bR[4][2];
#pragma unroll
        for (int mi = 0; mi < 4; mi++)
#pragma unroll
            for (int kk = 0; kk < 2; kk++)
                aR[mi][kk] = *(const bf16x8*)&Ab[(mi * 16 + fr) * 64 + ((kk * 4 + q) ^ sw) * 8];
#pragma unroll
        for (int ni = 0; ni < 4; ni++)
#pragma unroll
            for (int kk = 0; kk < 2; kk++)
                bR[ni][kk] = *(const bf16x8*)&Bb[(browoff + ni * 16 + fr) * 64 + ((kk * 4 + q) ^ sw) * 8];
        __builtin_amdgcn_s_setprio(1);
#pragma unroll
        for (int mi = 0; mi < 4; mi++)
#pragma unroll
            for (int ni = 0; ni < 4; ni++)
#pragma unroll
                for (int kk = 0; kk < 2; kk++)
                    acc[mi][ni] = __builtin_amdgcn_mfma_f32_16x16x32_bf16(aR[mi][kk], bR[ni][kk], acc[mi][ni], 0, 0, 0);
        __builtin_amdgcn_s_setprio(0);

        // region 2: read A(mi4-7); 32 MFMA
        bf16x8 a2[4][2];
#pragma unroll
        for (int mi = 0; mi < 4; mi++)
#pragma unroll
            for (int kk = 0; kk < 2; kk++)
                a2[mi][kk] = *(const bf16x8*)&Ab[((4 + mi) * 16 + fr) * 64 + ((kk * 4 + q) ^ sw) * 8];
        __builtin_amdgcn_s_setprio(1);
#pragma unroll
        for (int mi = 0; mi < 4; mi++)
#pragma unroll
            for (int ni = 0; ni < 4; ni++)
#pragma unroll
                for (int kk = 0; kk < 2; kk++)
                    acc[4 + mi][ni] = __builtin_amdgcn_mfma_f32_16x16x32_bf16(a2[mi][kk], bR[ni][kk], acc[4 + mi][ni], 0, 0, 0);
        __builtin_amdgcn_s_setprio(0);

        __builtin_amdgcn_s_barrier();      // all reads of cur drained
        if (hasN2) STAGE_TILE(cur, t + 2); // full t+2 into cur (8 loads)
        if (hasN1) {
            if (hasN2) { WAITV(8); } else { WAITV(0); }   // t+1 landed
            __builtin_amdgcn_sched_barrier(0);
        }
        __builtin_amdgcn_s_barrier();      // t+1 buffer published
    }
#undef STAGE_TILE

    const int cr = q * 4, cc = fr;
#pragma unroll
    for (int ni = 0; ni < 4; ni++) {
        size_t c = col0 + wc * 64 + ni * 16 + cc;
        float bv = bias ? bias[c] : 0.f;
#pragma unroll
        for (int mi = 0; mi < 8; mi++) {
            size_t r = row0 + wr * 128 + mi * 16 + cr;
#pragma unroll
            for (int j = 0; j < 4; j++) {
                float v = acc[mi][ni][j] + bv;
                if (EPI == 1) v = fmaxf(v, 0.f);
                C[(r + j) * ldc + c] = (bf16_t)v;
            }
        }
    }
}

// ---------------------------------------------------------------------------
// 128x128-tile GEMM, 4 waves, BK=64, double-buffered LDS (64 KiB).
// Same deep pipeline: full t+2 staged at mid-barrier, WAITV(8) at iter end.
// EPI: 0 bf16+bias, 1 +relu, 2 f32*scale, 3 bf16*scale
// ---------------------------------------------------------------------------
template <int EPI>
__global__ __launch_bounds__(256)
void gemm_db(const bf16_t* __restrict__ A, int lda, long sA,
             const bf16_t* __restrict__ Bt, int ldb, long sB,
             void* __restrict__ Cv, int ldc, long sC,
             const float* __restrict__ bias, int K, float scale)
{
    __shared__ bf16_t Asm[2][128 * 64];
    __shared__ bf16_t Bsm[2][128 * 64];
    const int tid = threadIdx.x, w = tid >> 6, l = tid & 63;
    const int bz = blockIdx.z;

    const int gx = gridDim.x;
    int lin = blockIdx.y * gx + blockIdx.x;
    const int nlin = gx * gridDim.y;
    lin = (lin & 7) * (nlin >> 3) + (lin >> 3);
    const size_t row0 = (size_t)(lin / gx) * 128;
    const size_t col0 = (size_t)(lin % gx) * 128;

    A  += (size_t)bz * sA;
    Bt += (size_t)bz * sB;

    const int lr = l >> 3;
    const int sl = (l & 7) ^ lr;
    const bf16_t* Ag = A  + (row0 + (size_t)(w * 32) + lr) * lda + sl * 8;
    const bf16_t* Bg = Bt + (col0 + (size_t)(w * 32) + lr) * ldb + sl * 8;
    const int wlds = (w * 32) * 64;

#define STAGE_TILE(buf, tt)                                                    \
    do { const int ko = (tt) * 64;                                             \
        _Pragma("unroll")                                                      \
        for (int c = 0; c < 4; c++) {                                          \
            gll16(&Asm[buf][wlds + c * 8 * 64], Ag + (size_t)(c * 8) * lda + ko); \
            gll16(&Bsm[buf][wlds + c * 8 * 64], Bg + (size_t)(c * 8) * ldb + ko); \
        }                                                                      \
    } while (0)

    const int wm = (w >> 1) * 64, wn = (w & 1) * 64;
    const int fr16 = l & 15, q4 = l >> 4, sw = l & 7;
    f32x4 acc[4][4] = {};
    const int NT = K >> 6;

    STAGE_TILE(0, 0);
    if (NT > 1) { STAGE_TILE(1, 1); WAITV(8); } else { WAITV(0); }
    __builtin_amdgcn_sched_barrier(0);
    __builtin_amdgcn_s_barrier();

    for (int t = 0; t < NT; ++t) {
        const int cur = t & 1;
        const bool hasN1 = (t + 1 < NT), hasN2 = (t + 2 < NT);

        bf16x8 a0[4], b0[4], a1[4], b1[4];
        const int s0 = (q4 ^ sw) * 8, s1 = ((4 + q4) ^ sw) * 8;
#pragma unroll
        for (int i = 0; i < 4; i++) {
            a0[i] = *(const bf16x8*)&Asm[cur][(wm + i * 16 + fr16) * 64 + s0];
            b0[i] = *(const bf16x8*)&Bsm[cur][(wn + i * 16 + fr16) * 64 + s0];
        }
        __builtin_amdgcn_s_setprio(1);
#pragma unroll
        for (int mi = 0; mi < 4; mi++)
#pragma unroll
            for (int ni = 0; ni < 4; ni++)
                acc[mi][ni] = __builtin_amdgcn_mfma_f32_16x16x32_bf16(a0[mi], b0[ni], acc[mi][ni], 0, 0, 0);
        __builtin_amdgcn_s_setprio(0);
#pragma unroll
        for (int i = 0; i < 4; i++) {
            a1[i] = *(const bf16x8*)&Asm[cur][(wm + i * 16 + fr16) * 64 + s1];
            b1[i] = *(const bf16x8*)&Bsm[cur][(wn + i * 16 + fr16) * 64 + s1];
        }
        __builtin_amdgcn_s_setprio(1);
#pragma unroll
        for (int mi = 0; mi < 4; mi++)
#pragma unroll
            for (int ni = 0; ni < 4; ni++)
                acc[mi][ni] = __builtin_amdgcn_mfma_f32_16x16x32_bf16(a1[mi], b1[ni], acc[mi][ni], 0, 0, 0);
        __builtin_amdgcn_s_setprio(0);

        __builtin_amdgcn_s_barrier();      // reads of cur drained
        if (hasN2) STAGE_TILE(cur, t + 2);
        if (hasN1) {
            if (hasN2) { WAITV(8); } else { WAITV(0); }
            __builtin_amdgcn_sched_barrier(0);
        }
        __builtin_amdgcn_s_barrier();
    }
#undef STAGE_TILE

    const int cr = q4 * 4, cc = fr16;
    if (EPI == 2) {
        float* C = (float*)Cv + (size_t)bz * sC;
#pragma unroll
        for (int mi = 0; mi < 4; mi++)
#pragma unroll
            for (int ni = 0; ni < 4; ni++) {
                size_t r = row0 + wm + mi * 16 + cr;
                size_t c = col0 + wn + ni * 16 + cc;
#pragma unroll
                for (int j = 0; j < 4; j++)
                    C[(r + j) * ldc + c] = acc[mi][ni][j] * scale;
            }
    } else if (EPI == 3) {
        bf16_t* C = (bf16_t*)Cv + (size_t)bz * sC;
#pragma unroll
        for (int mi = 0; mi < 4; mi++)
#pragma unroll
            for (int ni = 0; ni < 4; ni++) {
                size_t r = row0 + wm + mi * 16 + cr;
                size_t c = col0 + wn + ni * 16 + cc;
#pragma unroll
                for (int j = 0; j < 4; j++)
                    C[(r + j) * ldc + c] = (bf16_t)(acc[mi][ni][j] * scale);
            }
    } else {
        bf16_t* C = (bf16_t*)Cv + (size_t)bz * sC;
#pragma unroll
        for (int ni = 0; ni < 4; ni++) {
            size_t c = col0 + wn + ni * 16 + cc;
            float bv = bias ? bias[c] : 0.f;
#pragma unroll
            for (int mi = 0; mi < 4; mi++) {
                size_t r = row0 + wm + mi * 16 + cr;
#pragma unroll
                for (int j = 0; j < 4; j++) {
                    float v = acc[mi][ni][j] + bv;
                    if (EPI == 1) v = fmaxf(v, 0.f);
                    C[(r + j) * ldc + c] = (bf16_t)v;
                }
            }
        }
    }
}

// ---------------------------------------------------------------------------
// one-shot preprocessing: weight convert-transposes + bias concat + embed.
// ---------------------------------------------------------------------------
__global__ __launch_bounds__(256)
void prep_kernel(const float* __restrict__ Wq, const float* __restrict__ Wk,
                 const float* __restrict__ Wv, const float* __restrict__ Wf1,
                 const float* __restrict__ Wf2,
                 const float* __restrict__ bq, const float* __restrict__ bk,
                 const float* __restrict__ bv,
                 const int* __restrict__ ids, const float* __restrict__ emb,
                 bf16_t* __restrict__ wqkvTA, bf16_t* __restrict__ wf1TA,
                 bf16_t* __restrict__ wf2TA, float* __restrict__ qbiasA,
                 float* __restrict__ x, bf16_t* __restrict__ xb)
{
    __shared__ bf16_t tls[64 * 64];
    const size_t DD = 1024 * 1024;
    int id = blockIdx.x;
    if (id < 16896) {
        const float* src; bf16_t* dst; int ldin, ldout, bx, by;
        if (id < 4608) {
            int layer = id / 768, r = id % 768, which = r >> 8, t = r & 255;
            src = (which == 0 ? Wq : which == 1 ? Wk : Wv) + (size_t)layer * DD;
            dst = wqkvTA + (size_t)layer * 3 * DD + (size_t)which * DD;
            ldin = 1024; ldout = 1024; bx = (t & 15) * 64; by = (t >> 4) * 64;
        } else if (id < 10752) {
            int i = id - 4608, layer = i >> 10, t = i & 1023;
            src = Wf1 + (size_t)layer * 4 * DD; dst = wf1TA + (size_t)layer * 4 * DD;
            ldin = 4096; ldout = 1024; bx = (t & 63) * 64; by = (t >> 6) * 64;
        } else {
            int i = id - 10752, layer = i >> 10, t = i & 1023;
            src = Wf2 + (size_t)layer * 4 * DD; dst = wf2TA + (size_t)layer * 4 * DD;
            ldin = 1024; ldout = 4096; bx = (t & 15) * 64; by = (t >> 4) * 64;
        }
        const int tid = threadIdx.x;
        const int cg = tid & 15, ri = tid >> 4;
#pragma unroll
        for (int k = 0; k < 4; k++) {
            int r = ri + k * 16;
            float4 v = *(const float4*)&src[(size_t)(by + r) * ldin + bx + cg * 4];
            ushort4 o = {f2bf(v.x), f2bf(v.y), f2bf(v.z), f2bf(v.w)};
            int g = cg ^ ((r >> 2) & 15);
            *(ushort4*)&tls[r * 64 + g * 4] = o;
        }
        __syncthreads();
#pragma unroll
        for (int k = 0; k < 4; k++) {
            int i2 = ri + k * 16;
            int gr = (i2 >> 2) ^ cg;
            ushort4 o;
            o.x = __builtin_bit_cast(u16, tls[(cg * 4 + 0) * 64 + gr * 4 + (i2 & 3)]);
            o.y = __builtin_bit_cast(u16, tls[(cg * 4 + 1) * 64 + gr * 4 + (i2 & 3)]);
            o.z = __builtin_bit_cast(u16, tls[(cg * 4 + 2) * 64 + gr * 4 + (i2 & 3)]);
            o.w = __builtin_bit_cast(u16, tls[(cg * 4 + 3) * 64 + gr * 4 + (i2 & 3)]);
            *(ushort4*)&dst[(size_t)(bx + i2) * ldout + by + cg * 4] = o;
        }
        return;
    }
    id -= 16896;
    if (id < 72) {
        int i = id * 256 + threadIdx.x;
        int lyr = i / 3072, j = i - lyr * 3072;
        qbiasA[i] = (j < 1024) ? bq[lyr * 1024 + j]
                  : (j < 2048) ? bk[lyr * 1024 + j - 1024]
                               : bv[lyr * 1024 + j - 2048];
        return;
    }
    id -= 72;
    const int row = id;
    const int s = row & 1023;
    const int eid = ids[row];
    const float* er = emb + (size_t)eid * 1024;
    float* xr = x + (size_t)row * 1024;
    bf16_t* br = xb + (size_t)row * 1024;
#pragma unroll
    for (int k = 0; k < 2; k++) {
        int i = threadIdx.x + 256 * k;
        int d = 2 * i;
        float dv = expf((float)d * -0.008994473019508f);
        float ph = (float)s * dv;
        float sv, cv;
        sincosf(ph, &sv, &cv);
        float2 ev = *(const float2*)&er[d];
        float x0 = ev.x + sv;
        float x1 = ev.y + cv;
        float2 xo = {x0, x1};
        *(float2*)&xr[d] = xo;
        ushort2 bo = {f2bf(x0), f2bf(x1)};
        *(ushort2*)&br[d] = bo;
    }
}

// ---------------------------------------------------------------------------
// merged masked-softmax over bf16 scores (blocks 0..1023) + V^T transpose
// (blocks 1024..2047).
// ---------------------------------------------------------------------------
__global__ __launch_bounds__(256)
void softvt_kernel(const bf16_t* __restrict__ sc, const int* __restrict__ amask,
                   bf16_t* __restrict__ p, const bf16_t* __restrict__ qkv,
                   bf16_t* __restrict__ vt)
{
    __shared__ bf16_t tls[64][72];
    int bid = blockIdx.x;
    if (bid < 1024) {
        const int row = bid * 4 + (threadIdx.x >> 6);
        const int l = threadIdx.x & 63;
        const int b = row >> 10;
        const bf16_t* s = sc + (size_t)row * 1024;
        const int* m = amask + (size_t)b * 1024;
        float v[16];
        float mx = -3.0e38f;
#pragma unroll
        for (int i = 0; i < 4; i++) {
            int c = 4 * l + 256 * i;
            ushort4 su = *(const ushort4*)&s[c];
            int4 mv = *(const int4*)&m[c];
            v[4 * i + 0] = mv.x ? bf2f(su.x) : -1e9f;
            v[4 * i + 1] = mv.y ? bf2f(su.y) : -1e9f;
            v[4 * i + 2] = mv.z ? bf2f(su.z) : -1e9f;
            v[4 * i + 3] = mv.w ? bf2f(su.w) : -1e9f;
            mx = fmaxf(mx, fmaxf(fmaxf(v[4 * i], v[4 * i + 1]), fmaxf(v[4 * i + 2], v[4 * i + 3])));
        }
#pragma unroll
        for (int o = 32; o; o >>= 1) mx = fmaxf(mx, __shfl_xor(mx, o, 64));
        float sum = 0.f;
#pragma unroll
        for (int i = 0; i < 16; i++) { v[i] = __expf(v[i] - mx); sum += v[i]; }
#pragma unroll
        for (int o = 32; o; o >>= 1) sum += __shfl_xor(sum, o, 64);
        float inv = 1.0f / sum;
#pragma unroll
        for (int i = 0; i < 4; i++) {
            int c = 4 * l + 256 * i;
            ushort4 st;
            st.x = f2bf(v[4 * i + 0] * inv);
            st.y = f2bf(v[4 * i + 1] * inv);
            st.z = f2bf(v[4 * i + 2] * inv);
            st.w = f2bf(v[4 * i + 3] * inv);
            *(ushort4*)&p[(size_t)row * 1024 + c] = st;
        }
        return;
    }
    bid -= 1024;
    const int z = bid >> 8, t = bid & 255;
    const bf16_t* in = qkv + 2048 + (size_t)z * 1024 * 3072;
    bf16_t* out = vt + (size_t)z * 1024 * 1024;
    const int bx = (t & 15) * 64, by = (t >> 4) * 64;
    const int tid = threadIdx.x;
    const int cj = (tid & 15) * 4, ri = tid >> 4;
#pragma unroll
    for (int k = 0; k < 4; k++) {
        int r = ri + k * 16;
        *(ushort4*)&tls[r][cj] = *(const ushort4*)&in[(size_t)(by + r) * 3072 + bx + cj];
    }
    __syncthreads();
#pragma unroll
    for (int k = 0; k < 4; k++) {
        int i2 = ri + k * 16;
        ushort4 o;
        o.x = __builtin_bit_cast(u16, tls[cj + 0][i2]);
        o.y = __builtin_bit_cast(u16, tls[cj + 1][i2]);
        o.z = __builtin_bit_cast(u16, tls[cj + 2][i2]);
        o.w = __builtin_bit_cast(u16, tls[cj + 3][i2]);
        *(ushort4*)&out[(size_t)(bx + i2) * 1024 + by + cj] = o;
    }
}

// ---------------------------------------------------------------------------
// residual + LayerNorm: t = xin + add; y = LN(t)*g + beta
// ---------------------------------------------------------------------------
__global__ __launch_bounds__(256)
void ln_kernel(const float* __restrict__ xin, const bf16_t* __restrict__ add,
               const float* __restrict__ g, const float* __restrict__ beta,
               float* __restrict__ xout, bf16_t* __restrict__ bout)
{
    __shared__ float red[8];
    const int row = blockIdx.x;
    const int t = threadIdx.x;
    const size_t base = (size_t)row * 1024 + t * 4;
    float4 xv = *(const float4*)&xin[base];
    ushort4 au = *(const ushort4*)&add[base];
    float tv[4];
    tv[0] = xv.x + bf2f(au.x);
    tv[1] = xv.y + bf2f(au.y);
    tv[2] = xv.z + bf2f(au.z);
    tv[3] = xv.w + bf2f(au.w);
    float s = tv[0] + tv[1] + tv[2] + tv[3];
    float s2 = tv[0] * tv[0] + tv[1] * tv[1] + tv[2] * tv[2] + tv[3] * tv[3];
#pragma unroll
    for (int o = 32; o; o >>= 1) { s += __shfl_xor(s, o, 64); s2 += __shfl_xor(s2, o, 64); }
    if ((t & 63) == 0) { red[t >> 6] = s; red[4 + (t >> 6)] = s2; }
    __syncthreads();
    s = red[0] + red[1] + red[2] + red[3];
    s2 = red[4] + red[5] + red[6] + red[7];
    const float mu = s * (1.f / 1024.f);
    const float var = s2 * (1.f / 1024.f) - mu * mu;
    const float rs = rsqrtf(var + 1e-5f);
    float4 gu = *(const float4*)&g[t * 4];
    float4 bu = *(const float4*)&beta[t * 4];
    float y0 = (tv[0] - mu) * rs * gu.x + bu.x;
    float y1 = (tv[1] - mu) * rs * gu.y + bu.y;
    float y2 = (tv[2] - mu) * rs * gu.z + bu.z;
    float y3 = (tv[3] - mu) * rs * gu.w + bu.w;
    float4 yo = {y0, y1, y2, y3};
    *(float4*)&xout[base] = yo;
    ushort4 ob = {f2bf(y0), f2bf(y1), f2bf(y2), f2bf(y3)};
    *(ushort4*)&bout[base] = ob;
}

// ---------------------------------------------------------------------------
// residual + 4-plane-sum + bias + LayerNorm (for split-K FF2)
// ---------------------------------------------------------------------------
__global__ __launch_bounds__(256)
void ln4_kernel(const float* __restrict__ xin, const bf16_t* __restrict__ p,
                long pstride, const float* __restrict__ fbias,
                const float* __restrict__ g, const float* __restrict__ beta,
                float* __restrict__ xout, bf16_t* __restrict__ bout)
{
    __shared__ float red[8];
    const int row = blockIdx.x;
    const int t = threadIdx.x;
    const size_t base = (size_t)row * 1024 + t * 4;
    float4 xv = *(const float4*)&xin[base];
    float4 bb = *(const float4*)&fbias[t * 4];
    float tv[4] = {xv.x + bb.x, xv.y + bb.y, xv.z + bb.z, xv.w + bb.w};
#pragma unroll
    for (int z = 0; z < 4; z++) {
        ushort4 au = *(const ushort4*)&p[(size_t)z * pstride + base];
        tv[0] += bf2f(au.x); tv[1] += bf2f(au.y);
        tv[2] += bf2f(au.z); tv[3] += bf2f(au.w);
    }
    float s = tv[0] + tv[1] + tv[2] + tv[3];
    float s2 = tv[0] * tv[0] + tv[1] * tv[1] + tv[2] * tv[2] + tv[3] * tv[3];
#pragma unroll
    for (int o = 32; o; o >>= 1) { s += __shfl_xor(s, o, 64); s2 += __shfl_xor(s2, o, 64); }
    if ((t & 63) == 0) { red[t >> 6] = s; red[4 + (t >> 6)] = s2; }
    __syncthreads();
    s = red[0] + red[1] + red[2] + red[3];
    s2 = red[4] + red[5] + red[6] + red[7];
    const float mu = s * (1.f / 1024.f);
    const float var = s2 * (1.f / 1024.f) - mu * mu;
    const float rs = rsqrtf(var + 1e-5f);
    float4 gu = *(const float4*)&g[t * 4];
    float4 bu = *(const float4*)&beta[t * 4];
    float y0 = (tv[0] - mu) * rs * gu.x + bu.x;
    float y1 = (tv[1] - mu) * rs * gu.y + bu.y;
    float y2 = (tv[2] - mu) * rs * gu.z + bu.z;
    float y3 = (tv[3] - mu) * rs * gu.w + bu.w;
    float4 yo = {y0, y1, y2, y3};
    *(float4*)&xout[base] = yo;
    ushort4 ob = {f2bf(y0), f2bf(y1), f2bf(y2), f2bf(y3)};
    *(ushort4*)&bout[base] = ob;
}

// ---------------------------------------------------------------------------

extern "C" void kernel_launch(void* const* d_in, const int* in_sizes, int n_in,
                              void* d_out, int out_size, void* d_ws, size_t ws_size,
                              hipStream_t stream)
{
    const int*   ids = (const int*)d_in[0];
    const int*   am  = (const int*)d_in[1];
    const float* emb = (const float*)d_in[2];
    const float* Wq  = (const float*)d_in[3];
    const float* Wk  = (const float*)d_in[4];
    const float* Wv  = (const float*)d_in[5];
    const float* bq  = (const float*)d_in[6];
    const float* bk  = (const float*)d_in[7];
    const float* bv  = (const float*)d_in[8];
    const float* g1  = (const float*)d_in[9];
    const float* be1 = (const float*)d_in[10];
    const float* Wf1 = (const float*)d_in[11];
    const float* bf1 = (const float*)d_in[12];
    const float* Wf2 = (const float*)d_in[13];
    const float* bf2_ = (const float*)d_in[14];
    const float* g2  = (const float*)d_in[15];
    const float* be2 = (const float*)d_in[16];

    char* ws = (char*)d_ws;
    float*  x      = (float*)(ws);                      // 16 MB  [0,16)
    bf16_t* xb     = (bf16_t*)(ws + (16LL << 20));      // 8 MB   [16,24)
    bf16_t* qkv    = (bf16_t*)(ws + (24LL << 20));      // 24 MB  [24,48)
    bf16_t* vt     = (bf16_t*)(ws + (48LL << 20));      // 8 MB   [48,56)
    bf16_t* fpart  = (bf16_t*)(ws + (24LL << 20));      // 32 MB  [24,56) (aliases qkv/vt)
    bf16_t* scores = (bf16_t*)(ws + (56LL << 20));      // 8 MB   [56,64) (aliases h)
    bf16_t* p      = (bf16_t*)(ws + (72LL << 20));      // 8 MB   [72,80) (aliases h)
    bf16_t* h      = (bf16_t*)(ws + (56LL << 20));      // 32 MB  [56,88)
    bf16_t* attn   = (bf16_t*)(ws + (88LL << 20));      // 8 MB   [88,96)
    bf16_t* wqkvTA = (bf16_t*)(ws + (96LL << 20));      // 36 MB  [96,132)
    bf16_t* wf1TA  = (bf16_t*)(ws + (132LL << 20));     // 48 MB  [132,180)
    bf16_t* wf2TA  = (bf16_t*)(ws + (180LL << 20));     // 48 MB  [180,228)
    float*  qbiasA = (float*)(ws + (228LL << 20));      // 72 KB

    const size_t DD = 1024 * 1024;

    prep_kernel<<<21064, 256, 0, stream>>>(Wq, Wk, Wv, Wf1, Wf2, bq, bk, bv,
                                           ids, emb, wqkvTA, wf1TA, wf2TA, qbiasA, x, xb);

    for (int l = 0; l < 6; l++) {
        // fused QKV: [4096,1024] x [3072,1024]^T -> qkv [4096,3072]
        gemm8p<0><<<dim3(12, 16, 1), 512, 0, stream>>>(xb, 1024, wqkvTA + (size_t)l * 3 * DD, 1024,
                                                       qkv, 3072, qbiasA + l * 3072, 1024, 0, 0);
        // scores = Q K^T * 1/32  (bf16)
        gemm_db<3><<<dim3(8, 8, 4), 256, 0, stream>>>(qkv, 3072, 1024L * 3072,
                                                      qkv + 1024, 3072, 1024L * 3072,
                                                      scores, 1024, 1024L * 1024,
                                                      nullptr, 1024, 0.03125f);
        // softmax + V^T (merged)
        softvt_kernel<<<2048, 256, 0, stream>>>(scores, am, p, qkv, vt);
        // attn = P V  (via V^T as Bt)
        gemm_db<0><<<dim3(8, 8, 4), 256, 0, stream>>>(p, 1024, 1024L * 1024,
                                                      vt, 1024, 1024L * 1024,
                                                      attn, 1024, 1024L * 1024,
                                                      nullptr, 1024, 0.f);
        ln_kernel<<<4096, 256, 0, stream>>>(x, attn, g1 + l * 1024, be1 + l * 1024, x, xb);
        // FF1 with relu -> h [4096,4096]
        gemm8p<1><<<dim3(16, 16, 1), 512, 0, stream>>>(xb, 1024, wf1TA + (size_t)l * 4 * DD, 1024,
                                                       h, 4096, bf1 + l * 4096, 1024, 0, 0);
        // FF2 split-K=4 -> fpart
        gemm8p<0><<<dim3(4, 16, 4), 512, 0, stream>>>(h, 4096, wf2TA + (size_t)l * 4 * DD, 4096,
                                                      fpart, 1024, nullptr, 1024,
                                                      1024, 4096L * 1024);
        float* xo = (l == 5) ? (float*)d_out : x;
        ln4_kernel<<<4096, 256, 0, stream>>>(x, fpart, 4096L * 1024, bf2_ + l * 1024,
                                             g2 + l * 1024, be2 + l * 1024, xo, xb);
    }
    (void)in_sizes; (void)n_in; (void)out_size; (void)ws_size;
}

// Round 10
// 1219.694 us; speedup vs baseline: 1.1220x; 1.1220x over previous
//
#include <hip/hip_runtime.h>

typedef __bf16 bf16_t;
typedef __bf16 bf16x8 __attribute__((ext_vector_type(8)));
typedef float f32x4 __attribute__((ext_vector_type(4)));
typedef float f32x16 __attribute__((ext_vector_type(16)));
typedef unsigned short u16;

#define DEV static __device__ __forceinline__

DEV float bf2f(u16 u) { __bf16 h = __builtin_bit_cast(__bf16, u); return (float)h; }
DEV u16 f2bf(float f) { __bf16 h = (__bf16)f; return __builtin_bit_cast(u16, h); }

// async global->LDS, 16B per lane; lds base must be wave-uniform.
DEV void gll16(bf16_t* lds, const bf16_t* g) {
    __builtin_amdgcn_global_load_lds(
        (const __attribute__((address_space(1))) void*)g,
        (__attribute__((address_space(3))) void*)lds, 16, 0, 0);
}

#define WAITV(N) asm volatile("s_waitcnt vmcnt(" #N ")" ::: "memory")

// ---------------------------------------------------------------------------
// 256x256-tile GEMM, 8 waves (2M x 4N), BK=64, double-buffered 128KiB LDS,
// round-8 schedule (pairs staged inside compute regions, WAITV(2)), but inner
// math on v_mfma_f32_32x32x16_bf16 (2495 TF ceiling vs 2075 for 16x16).
// Per wave: 128x64 out = 4x2 tiles of 32x32; per K-tile: 4 ks x 8 tiles.
// A frag: lane l holds row (l&31), k = ks*16 + (l>>5)*8 + j. C/D: col=l&31,
// row=(reg&3)+8*(reg>>2)+4*(l>>5)  [m74/m101].
// EPI: 0 = bf16 out (+f32 bias if non-null), 1 = bf16 out + bias + relu
// ---------------------------------------------------------------------------
template <int EPI>
__global__ __launch_bounds__(512, 1)
void gemm8p(const bf16_t* __restrict__ A, int lda,
            const bf16_t* __restrict__ Bt, int ldb,
            bf16_t* __restrict__ C, int ldc,
            const float* __restrict__ bias, int K,
            long kadv, long cadv)
{
    __shared__ bf16_t Asm[2 * 2 * 8192];   // [buf][half][128*64]
    __shared__ bf16_t Bsm[2 * 2 * 8192];
    const int tid = threadIdx.x, w = tid >> 6, l = tid & 63;
    const int z = blockIdx.z;
    A  += (size_t)z * kadv;
    Bt += (size_t)z * kadv;
    C  += (size_t)z * cadv;

    const int gx = gridDim.x;
    int lin = blockIdx.y * gx + blockIdx.x;
    const int nlin = gx * gridDim.y;
    lin = (lin & 7) * (nlin >> 3) + (lin >> 3);
    const size_t row0 = (size_t)(lin / gx) * 256;
    const size_t col0 = (size_t)(lin % gx) * 256;

    const int wr = w >> 2, wc = w & 3;
    const int bh = wc >> 1;
    const int browoff = (wc & 1) * 64;     // 0 or 64 within the 128-col B half
    const int r32 = l & 31, hk = l >> 5, sw = l & 7;

    const int srow = w * 8 + (l >> 3);
    const int sslot8 = ((l & 7) ^ ((l >> 3) & 7)) * 8;
    const bf16_t* AgH0 = A  + (row0 + srow) * (size_t)lda + sslot8;
    const bf16_t* BgH0 = Bt + (col0 + srow) * (size_t)ldb + sslot8;
    const size_t a128 = (size_t)128 * lda, b128 = (size_t)128 * ldb;
    const size_t a64  = (size_t)64 * lda,  b64  = (size_t)64 * ldb;
    const int wlds = w * 512;

#define STAGE_PAIR(buf, tt, p)                                                 \
    do {                                                                       \
        const int koff = (tt) * 64;                                            \
        if ((p) == 0) {                                                        \
            gll16(Asm + ((buf)*2+0)*8192 + wlds,        AgH0 + koff);          \
            gll16(Asm + ((buf)*2+0)*8192 + 4096 + wlds, AgH0 + koff + a64);    \
        } else if ((p) == 1) {                                                 \
            gll16(Asm + ((buf)*2+1)*8192 + wlds,        AgH0 + a128 + koff);   \
            gll16(Asm + ((buf)*2+1)*8192 + 4096 + wlds, AgH0 + a128 + koff + a64); \
        } else if ((p) == 2) {                                                 \
            gll16(Bsm + ((buf)*2+0)*8192 + wlds,        BgH0 + koff);          \
            gll16(Bsm + ((buf)*2+0)*8192 + 4096 + wlds, BgH0 + koff + b64);    \
        } else {                                                               \
            gll16(Bsm + ((buf)*2+1)*8192 + wlds,        BgH0 + b128 + koff);   \
            gll16(Bsm + ((buf)*2+1)*8192 + 4096 + wlds, BgH0 + b128 + koff + b64); \
        }                                                                      \
    } while (0)

    f32x16 acc[4][2] = {};
    const int NT = K >> 6;

    STAGE_PAIR(0, 0, 0); STAGE_PAIR(0, 0, 1); STAGE_PAIR(0, 0, 2); STAGE_PAIR(0, 0, 3);
    if (NT > 1) { STAGE_PAIR(1, 1, 0); WAITV(2); } else { WAITV(0); }
    __builtin_amdgcn_sched_barrier(0);
    __builtin_amdgcn_s_barrier();

    for (int t = 0; t < NT; ++t) {
        const int cur = t & 1, nxt = cur ^ 1;
        const bool hasN1 = (t + 1 < NT), hasN2 = (t + 2 < NT);
        const bf16_t* Ab = Asm + (cur * 2 + wr) * 8192;
        const bf16_t* Bb = Bsm + (cur * 2 + bh) * 8192;

        // region 1: read B(all 2ni x 4ks) + A(mi0-1); stage t+1 pairs 1,2; 16 MFMA
        bf16x8 bR[2][4], aR[2][4];
#pragma unroll
        for (int ni = 0; ni < 2; ni++)
#pragma unroll
            for (int ks = 0; ks < 4; ks++)
                bR[ni][ks] = *(const bf16x8*)&Bb[(browoff + ni * 32 + r32) * 64 + ((ks * 2 + hk) ^ sw) * 8];
#pragma unroll
        for (int mi = 0; mi < 2; mi++)
#pragma unroll
            for (int ks = 0; ks < 4; ks++)
                aR[mi][ks] = *(const bf16x8*)&Ab[(mi * 32 + r32) * 64 + ((ks * 2 + hk) ^ sw) * 8];
        if (hasN1) { STAGE_PAIR(nxt, t + 1, 1); STAGE_PAIR(nxt, t + 1, 2); }
        __builtin_amdgcn_s_setprio(1);
#pragma unroll
        for (int mi = 0; mi < 2; mi++)
#pragma unroll
            for (int ni = 0; ni < 2; ni++)
#pragma unroll
                for (int ks = 0; ks < 4; ks++)
                    acc[mi][ni] = __builtin_amdgcn_mfma_f32_32x32x16_bf16(aR[mi][ks], bR[ni][ks], acc[mi][ni], 0, 0, 0);
        __builtin_amdgcn_s_setprio(0);

        // region 2: read A(mi2-3); stage t+1 pair 3; 16 MFMA
        bf16x8 a2[2][4];
#pragma unroll
        for (int mi = 0; mi < 2; mi++)
#pragma unroll
            for (int ks = 0; ks < 4; ks++)
                a2[mi][ks] = *(const bf16x8*)&Ab[((2 + mi) * 32 + r32) * 64 + ((ks * 2 + hk) ^ sw) * 8];
        if (hasN1) STAGE_PAIR(nxt, t + 1, 3);
        __builtin_amdgcn_s_setprio(1);
#pragma unroll
        for (int mi = 0; mi < 2; mi++)
#pragma unroll
            for (int ni = 0; ni < 2; ni++)
#pragma unroll
                for (int ks = 0; ks < 4; ks++)
                    acc[2 + mi][ni] = __builtin_amdgcn_mfma_f32_32x32x16_bf16(a2[mi][ks], bR[ni][ks], acc[2 + mi][ni], 0, 0, 0);
        __builtin_amdgcn_s_setprio(0);

        __builtin_amdgcn_s_barrier();      // all reads of cur drained
        if (hasN2) STAGE_PAIR(cur, t + 2, 0);
        if (hasN1) {
            if (hasN2) { WAITV(2); } else { WAITV(0); }
            __builtin_amdgcn_sched_barrier(0);
        }
        __builtin_amdgcn_s_barrier();      // t+1 buffer published
    }
#undef STAGE_PAIR

    // epilogue: 32x32 C/D layout  col=l&31, row=(reg&3)+8*(reg>>2)+4*(l>>5)
#pragma unroll
    for (int ni = 0; ni < 2; ni++) {
        size_t c = col0 + wc * 64 + ni * 32 + r32;
        float bv = bias ? bias[c] : 0.f;
#pragma unroll
        for (int mi = 0; mi < 4; mi++) {
            size_t rb = row0 + wr * 128 + mi * 32 + hk * 4;
#pragma unroll
            for (int reg = 0; reg < 16; reg++) {
                size_t r = rb + (reg & 3) + 8 * (reg >> 2);
                float v = acc[mi][ni][reg] + bv;
                if (EPI == 1) v = fmaxf(v, 0.f);
                C[r * ldc + c] = (bf16_t)v;
            }
        }
    }
}

// ---------------------------------------------------------------------------
// 128x128-tile GEMM, 4 waves, BK=64, double-buffered LDS (64 KiB), round-8
// schedule (STB in region1, STA(t+2) at mid-barrier, WAITV(4)); 32x32x16 MFMA.
// Per wave: 64x64 out = 2x2 tiles of 32x32 x 4 ks.
// EPI: 0 bf16+bias, 1 +relu, 2 f32*scale, 3 bf16*scale
// ---------------------------------------------------------------------------
template <int EPI>
__global__ __launch_bounds__(256)
void gemm_db(const bf16_t* __restrict__ A, int lda, long sA,
             const bf16_t* __restrict__ Bt, int ldb, long sB,
             void* __restrict__ Cv, int ldc, long sC,
             const float* __restrict__ bias, int K, float scale)
{
    __shared__ bf16_t Asm[2][128 * 64];
    __shared__ bf16_t Bsm[2][128 * 64];
    const int tid = threadIdx.x, w = tid >> 6, l = tid & 63;
    const int bz = blockIdx.z;

    const int gx = gridDim.x;
    int lin = blockIdx.y * gx + blockIdx.x;
    const int nlin = gx * gridDim.y;
    lin = (lin & 7) * (nlin >> 3) + (lin >> 3);
    const size_t row0 = (size_t)(lin / gx) * 128;
    const size_t col0 = (size_t)(lin % gx) * 128;

    A  += (size_t)bz * sA;
    Bt += (size_t)bz * sB;

    const int lr = l >> 3;
    const int sl = (l & 7) ^ lr;
    const bf16_t* Ag = A  + (row0 + (size_t)(w * 32) + lr) * lda + sl * 8;
    const bf16_t* Bg = Bt + (col0 + (size_t)(w * 32) + lr) * ldb + sl * 8;
    const int wlds = (w * 32) * 64;

#define STA(buf, tt)                                                           \
    do { const int ko = (tt) * 64;                                             \
        _Pragma("unroll")                                                      \
        for (int c = 0; c < 4; c++)                                            \
            gll16(&Asm[buf][wlds + c * 8 * 64], Ag + (size_t)(c * 8) * lda + ko); \
    } while (0)
#define STB(buf, tt)                                                           \
    do { const int ko = (tt) * 64;                                             \
        _Pragma("unroll")                                                      \
        for (int c = 0; c < 4; c++)                                            \
            gll16(&Bsm[buf][wlds + c * 8 * 64], Bg + (size_t)(c * 8) * ldb + ko); \
    } while (0)

    const int wm = (w >> 1) * 64, wn = (w & 1) * 64;
    const int r32 = l & 31, hk = l >> 5, sw = l & 7;
    f32x16 acc[2][2] = {};
    const int NT = K >> 6;

    STA(0, 0); STB(0, 0);
    if (NT > 1) { STA(1, 1); WAITV(4); } else { WAITV(0); }
    __builtin_amdgcn_sched_barrier(0);
    __builtin_amdgcn_s_barrier();

    for (int t = 0; t < NT; ++t) {
        const int cur = t & 1, nxt = cur ^ 1;
        const bool hasN1 = (t + 1 < NT), hasN2 = (t + 2 < NT);

        // frags for ks=0,1; stage B(t+1); 8 MFMA
        bf16x8 a0[2][2], b0[2][2];
#pragma unroll
        for (int i = 0; i < 2; i++)
#pragma unroll
            for (int ks = 0; ks < 2; ks++) {
                a0[i][ks] = *(const bf16x8*)&Asm[cur][(wm + i * 32 + r32) * 64 + ((ks * 2 + hk) ^ sw) * 8];
                b0[i][ks] = *(const bf16x8*)&Bsm[cur][(wn + i * 32 + r32) * 64 + ((ks * 2 + hk) ^ sw) * 8];
            }
        if (hasN1) STB(nxt, t + 1);
        __builtin_amdgcn_s_setprio(1);
#pragma unroll
        for (int mi = 0; mi < 2; mi++)
#pragma unroll
            for (int ni = 0; ni < 2; ni++)
#pragma unroll
                for (int ks = 0; ks < 2; ks++)
                    acc[mi][ni] = __builtin_amdgcn_mfma_f32_32x32x16_bf16(a0[mi][ks], b0[ni][ks], acc[mi][ni], 0, 0, 0);
        __builtin_amdgcn_s_setprio(0);

        // frags for ks=2,3; 8 MFMA
        bf16x8 a1[2][2], b1[2][2];
#pragma unroll
        for (int i = 0; i < 2; i++)
#pragma unroll
            for (int ks = 0; ks < 2; ks++) {
                a1[i][ks] = *(const bf16x8*)&Asm[cur][(wm + i * 32 + r32) * 64 + (((2 + ks) * 2 + hk) ^ sw) * 8];
                b1[i][ks] = *(const bf16x8*)&Bsm[cur][(wn + i * 32 + r32) * 64 + (((2 + ks) * 2 + hk) ^ sw) * 8];
            }
        __builtin_amdgcn_s_setprio(1);
#pragma unroll
        for (int mi = 0; mi < 2; mi++)
#pragma unroll
            for (int ni = 0; ni < 2; ni++)
#pragma unroll
                for (int ks = 0; ks < 2; ks++)
                    acc[mi][ni] = __builtin_amdgcn_mfma_f32_32x32x16_bf16(a1[mi][ks], b1[ni][ks], acc[mi][ni], 0, 0, 0);
        __builtin_amdgcn_s_setprio(0);

        __builtin_amdgcn_s_barrier();      // reads of cur drained
        if (hasN2) STA(cur, t + 2);
        if (hasN1) {
            if (hasN2) { WAITV(4); } else { WAITV(0); }
            __builtin_amdgcn_sched_barrier(0);
        }
        __builtin_amdgcn_s_barrier();
    }
#undef STA
#undef STB

#pragma unroll
    for (int ni = 0; ni < 2; ni++) {
        size_t c = col0 + wn + ni * 32 + r32;
        float bv = (EPI == 0 || EPI == 1) ? (bias ? bias[c] : 0.f) : 0.f;
#pragma unroll
        for (int mi = 0; mi < 2; mi++) {
            size_t rb = row0 + wm + mi * 32 + hk * 4;
#pragma unroll
            for (int reg = 0; reg < 16; reg++) {
                size_t r = rb + (reg & 3) + 8 * (reg >> 2);
                float v = acc[mi][ni][reg];
                if (EPI == 2) {
                    ((float*)Cv + (size_t)bz * sC)[r * ldc + c] = v * scale;
                } else if (EPI == 3) {
                    ((bf16_t*)Cv + (size_t)bz * sC)[r * ldc + c] = (bf16_t)(v * scale);
                } else {
                    v += bv;
                    if (EPI == 1) v = fmaxf(v, 0.f);
                    ((bf16_t*)Cv + (size_t)bz * sC)[r * ldc + c] = (bf16_t)v;
                }
            }
        }
    }
}

// ---------------------------------------------------------------------------
// one-shot preprocessing: weight convert-transposes + bias concat + embed.
// ---------------------------------------------------------------------------
__global__ __launch_bounds__(256)
void prep_kernel(const float* __restrict__ Wq, const float* __restrict__ Wk,
                 const float* __restrict__ Wv, const float* __restrict__ Wf1,
                 const float* __restrict__ Wf2,
                 const float* __restrict__ bq, const float* __restrict__ bk,
                 const float* __restrict__ bv,
                 const int* __restrict__ ids, const float* __restrict__ emb,
                 bf16_t* __restrict__ wqkvTA, bf16_t* __restrict__ wf1TA,
                 bf16_t* __restrict__ wf2TA, float* __restrict__ qbiasA,
                 float* __restrict__ x, bf16_t* __restrict__ xb)
{
    __shared__ bf16_t tls[64 * 64];
    const size_t DD = 1024 * 1024;
    int id = blockIdx.x;
    if (id < 16896) {
        const float* src; bf16_t* dst; int ldin, ldout, bx, by;
        if (id < 4608) {
            int layer = id / 768, r = id % 768, which = r >> 8, t = r & 255;
            src = (which == 0 ? Wq : which == 1 ? Wk : Wv) + (size_t)layer * DD;
            dst = wqkvTA + (size_t)layer * 3 * DD + (size_t)which * DD;
            ldin = 1024; ldout = 1024; bx = (t & 15) * 64; by = (t >> 4) * 64;
        } else if (id < 10752) {
            int i = id - 4608, layer = i >> 10, t = i & 1023;
            src = Wf1 + (size_t)layer * 4 * DD; dst = wf1TA + (size_t)layer * 4 * DD;
            ldin = 4096; ldout = 1024; bx = (t & 63) * 64; by = (t >> 6) * 64;
        } else {
            int i = id - 10752, layer = i >> 10, t = i & 1023;
            src = Wf2 + (size_t)layer * 4 * DD; dst = wf2TA + (size_t)layer * 4 * DD;
            ldin = 1024; ldout = 4096; bx = (t & 15) * 64; by = (t >> 4) * 64;
        }
        const int tid = threadIdx.x;
        const int cg = tid & 15, ri = tid >> 4;
#pragma unroll
        for (int k = 0; k < 4; k++) {
            int r = ri + k * 16;
            float4 v = *(const float4*)&src[(size_t)(by + r) * ldin + bx + cg * 4];
            ushort4 o = {f2bf(v.x), f2bf(v.y), f2bf(v.z), f2bf(v.w)};
            int g = cg ^ ((r >> 2) & 15);
            *(ushort4*)&tls[r * 64 + g * 4] = o;
        }
        __syncthreads();
#pragma unroll
        for (int k = 0; k < 4; k++) {
            int i2 = ri + k * 16;
            int gr = (i2 >> 2) ^ cg;
            ushort4 o;
            o.x = __builtin_bit_cast(u16, tls[(cg * 4 + 0) * 64 + gr * 4 + (i2 & 3)]);
            o.y = __builtin_bit_cast(u16, tls[(cg * 4 + 1) * 64 + gr * 4 + (i2 & 3)]);
            o.z = __builtin_bit_cast(u16, tls[(cg * 4 + 2) * 64 + gr * 4 + (i2 & 3)]);
            o.w = __builtin_bit_cast(u16, tls[(cg * 4 + 3) * 64 + gr * 4 + (i2 & 3)]);
            *(ushort4*)&dst[(size_t)(bx + i2) * ldout + by + cg * 4] = o;
        }
        return;
    }
    id -= 16896;
    if (id < 72) {
        int i = id * 256 + threadIdx.x;
        int lyr = i / 3072, j = i - lyr * 3072;
        qbiasA[i] = (j < 1024) ? bq[lyr * 1024 + j]
                  : (j < 2048) ? bk[lyr * 1024 + j - 1024]
                               : bv[lyr * 1024 + j - 2048];
        return;
    }
    id -= 72;
    const int row = id;
    const int s = row & 1023;
    const int eid = ids[row];
    const float* er = emb + (size_t)eid * 1024;
    float* xr = x + (size_t)row * 1024;
    bf16_t* br = xb + (size_t)row * 1024;
#pragma unroll
    for (int k = 0; k < 2; k++) {
        int i = threadIdx.x + 256 * k;
        int d = 2 * i;
        float dv = expf((float)d * -0.008994473019508f);
        float ph = (float)s * dv;
        float sv, cv;
        sincosf(ph, &sv, &cv);
        float2 ev = *(const float2*)&er[d];
        float x0 = ev.x + sv;
        float x1 = ev.y + cv;
        float2 xo = {x0, x1};
        *(float2*)&xr[d] = xo;
        ushort2 bo = {f2bf(x0), f2bf(x1)};
        *(ushort2*)&br[d] = bo;
    }
}

// ---------------------------------------------------------------------------
// merged masked-softmax over bf16 scores (blocks 0..1023) + V^T transpose
// (blocks 1024..2047).
// ---------------------------------------------------------------------------
__global__ __launch_bounds__(256)
void softvt_kernel(const bf16_t* __restrict__ sc, const int* __restrict__ amask,
                   bf16_t* __restrict__ p, const bf16_t* __restrict__ qkv,
                   bf16_t* __restrict__ vt)
{
    __shared__ bf16_t tls[64][72];
    int bid = blockIdx.x;
    if (bid < 1024) {
        const int row = bid * 4 + (threadIdx.x >> 6);
        const int l = threadIdx.x & 63;
        const int b = row >> 10;
        const bf16_t* s = sc + (size_t)row * 1024;
        const int* m = amask + (size_t)b * 1024;
        float v[16];
        float mx = -3.0e38f;
#pragma unroll
        for (int i = 0; i < 4; i++) {
            int c = 4 * l + 256 * i;
            ushort4 su = *(const ushort4*)&s[c];
            int4 mv = *(const int4*)&m[c];
            v[4 * i + 0] = mv.x ? bf2f(su.x) : -1e9f;
            v[4 * i + 1] = mv.y ? bf2f(su.y) : -1e9f;
            v[4 * i + 2] = mv.z ? bf2f(su.z) : -1e9f;
            v[4 * i + 3] = mv.w ? bf2f(su.w) : -1e9f;
            mx = fmaxf(mx, fmaxf(fmaxf(v[4 * i], v[4 * i + 1]), fmaxf(v[4 * i + 2], v[4 * i + 3])));
        }
#pragma unroll
        for (int o = 32; o; o >>= 1) mx = fmaxf(mx, __shfl_xor(mx, o, 64));
        float sum = 0.f;
#pragma unroll
        for (int i = 0; i < 16; i++) { v[i] = __expf(v[i] - mx); sum += v[i]; }
#pragma unroll
        for (int o = 32; o; o >>= 1) sum += __shfl_xor(sum, o, 64);
        float inv = 1.0f / sum;
#pragma unroll
        for (int i = 0; i < 4; i++) {
            int c = 4 * l + 256 * i;
            ushort4 st;
            st.x = f2bf(v[4 * i + 0] * inv);
            st.y = f2bf(v[4 * i + 1] * inv);
            st.z = f2bf(v[4 * i + 2] * inv);
            st.w = f2bf(v[4 * i + 3] * inv);
            *(ushort4*)&p[(size_t)row * 1024 + c] = st;
        }
        return;
    }
    bid -= 1024;
    const int z = bid >> 8, t = bid & 255;
    const bf16_t* in = qkv + 2048 + (size_t)z * 1024 * 3072;
    bf16_t* out = vt + (size_t)z * 1024 * 1024;
    const int bx = (t & 15) * 64, by = (t >> 4) * 64;
    const int tid = threadIdx.x;
    const int cj = (tid & 15) * 4, ri = tid >> 4;
#pragma unroll
    for (int k = 0; k < 4; k++) {
        int r = ri + k * 16;
        *(ushort4*)&tls[r][cj] = *(const ushort4*)&in[(size_t)(by + r) * 3072 + bx + cj];
    }
    __syncthreads();
#pragma unroll
    for (int k = 0; k < 4; k++) {
        int i2 = ri + k * 16;
        ushort4 o;
        o.x = __builtin_bit_cast(u16, tls[cj + 0][i2]);
        o.y = __builtin_bit_cast(u16, tls[cj + 1][i2]);
        o.z = __builtin_bit_cast(u16, tls[cj + 2][i2]);
        o.w = __builtin_bit_cast(u16, tls[cj + 3][i2]);
        *(ushort4*)&out[(size_t)(bx + i2) * 1024 + by + cj] = o;
    }
}

// ---------------------------------------------------------------------------
// residual + LayerNorm: t = xin + add; y = LN(t)*g + beta
// ---------------------------------------------------------------------------
__global__ __launch_bounds__(256)
void ln_kernel(const float* __restrict__ xin, const bf16_t* __restrict__ add,
               const float* __restrict__ g, const float* __restrict__ beta,
               float* __restrict__ xout, bf16_t* __restrict__ bout)
{
    __shared__ float red[8];
    const int row = blockIdx.x;
    const int t = threadIdx.x;
    const size_t base = (size_t)row * 1024 + t * 4;
    float4 xv = *(const float4*)&xin[base];
    ushort4 au = *(const ushort4*)&add[base];
    float tv[4];
    tv[0] = xv.x + bf2f(au.x);
    tv[1] = xv.y + bf2f(au.y);
    tv[2] = xv.z + bf2f(au.z);
    tv[3] = xv.w + bf2f(au.w);
    float s = tv[0] + tv[1] + tv[2] + tv[3];
    float s2 = tv[0] * tv[0] + tv[1] * tv[1] + tv[2] * tv[2] + tv[3] * tv[3];
#pragma unroll
    for (int o = 32; o; o >>= 1) { s += __shfl_xor(s, o, 64); s2 += __shfl_xor(s2, o, 64); }
    if ((t & 63) == 0) { red[t >> 6] = s; red[4 + (t >> 6)] = s2; }
    __syncthreads();
    s = red[0] + red[1] + red[2] + red[3];
    s2 = red[4] + red[5] + red[6] + red[7];
    const float mu = s * (1.f / 1024.f);
    const float var = s2 * (1.f / 1024.f) - mu * mu;
    const float rs = rsqrtf(var + 1e-5f);
    float4 gu = *(const float4*)&g[t * 4];
    float4 bu = *(const float4*)&beta[t * 4];
    float y0 = (tv[0] - mu) * rs * gu.x + bu.x;
    float y1 = (tv[1] - mu) * rs * gu.y + bu.y;
    float y2 = (tv[2] - mu) * rs * gu.z + bu.z;
    float y3 = (tv[3] - mu) * rs * gu.w + bu.w;
    float4 yo = {y0, y1, y2, y3};
    *(float4*)&xout[base] = yo;
    ushort4 ob = {f2bf(y0), f2bf(y1), f2bf(y2), f2bf(y3)};
    *(ushort4*)&bout[base] = ob;
}

// ---------------------------------------------------------------------------
// residual + 4-plane-sum + bias + LayerNorm (for split-K FF2)
// ---------------------------------------------------------------------------
__global__ __launch_bounds__(256)
void ln4_kernel(const float* __restrict__ xin, const bf16_t* __restrict__ p,
                long pstride, const float* __restrict__ fbias,
                const float* __restrict__ g, const float* __restrict__ beta,
                float* __restrict__ xout, bf16_t* __restrict__ bout)
{
    __shared__ float red[8];
    const int row = blockIdx.x;
    const int t = threadIdx.x;
    const size_t base = (size_t)row * 1024 + t * 4;
    float4 xv = *(const float4*)&xin[base];
    float4 bb = *(const float4*)&fbias[t * 4];
    float tv[4] = {xv.x + bb.x, xv.y + bb.y, xv.z + bb.z, xv.w + bb.w};
#pragma unroll
    for (int z = 0; z < 4; z++) {
        ushort4 au = *(const ushort4*)&p[(size_t)z * pstride + base];
        tv[0] += bf2f(au.x); tv[1] += bf2f(au.y);
        tv[2] += bf2f(au.z); tv[3] += bf2f(au.w);
    }
    float s = tv[0] + tv[1] + tv[2] + tv[3];
    float s2 = tv[0] * tv[0] + tv[1] * tv[1] + tv[2] * tv[2] + tv[3] * tv[3];
#pragma unroll
    for (int o = 32; o; o >>= 1) { s += __shfl_xor(s, o, 64); s2 += __shfl_xor(s2, o, 64); }
    if ((t & 63) == 0) { red[t >> 6] = s; red[4 + (t >> 6)] = s2; }
    __syncthreads();
    s = red[0] + red[1] + red[2] + red[3];
    s2 = red[4] + red[5] + red[6] + red[7];
    const float mu = s * (1.f / 1024.f);
    const float var = s2 * (1.f / 1024.f) - mu * mu;
    const float rs = rsqrtf(var + 1e-5f);
    float4 gu = *(const float4*)&g[t * 4];
    float4 bu = *(const float4*)&beta[t * 4];
    float y0 = (tv[0] - mu) * rs * gu.x + bu.x;
    float y1 = (tv[1] - mu) * rs * gu.y + bu.y;
    float y2 = (tv[2] - mu) * rs * gu.z + bu.z;
    float y3 = (tv[3] - mu) * rs * gu.w + bu.w;
    float4 yo = {y0, y1, y2, y3};
    *(float4*)&xout[base] = yo;
    ushort4 ob = {f2bf(y0), f2bf(y1), f2bf(y2), f2bf(y3)};
    *(ushort4*)&bout[base] = ob;
}

// ---------------------------------------------------------------------------

extern "C" void kernel_launch(void* const* d_in, const int* in_sizes, int n_in,
                              void* d_out, int out_size, void* d_ws, size_t ws_size,
                              hipStream_t stream)
{
    const int*   ids = (const int*)d_in[0];
    const int*   am  = (const int*)d_in[1];
    const float* emb = (const float*)d_in[2];
    const float* Wq  = (const float*)d_in[3];
    const float* Wk  = (const float*)d_in[4];
    const float* Wv  = (const float*)d_in[5];
    const float* bq  = (const float*)d_in[6];
    const float* bk  = (const float*)d_in[7];
    const float* bv  = (const float*)d_in[8];
    const float* g1  = (const float*)d_in[9];
    const float* be1 = (const float*)d_in[10];
    const float* Wf1 = (const float*)d_in[11];
    const float* bf1 = (const float*)d_in[12];
    const float* Wf2 = (const float*)d_in[13];
    const float* bf2_ = (const float*)d_in[14];
    const float* g2  = (const float*)d_in[15];
    const float* be2 = (const float*)d_in[16];

    char* ws = (char*)d_ws;
    float*  x      = (float*)(ws);                      // 16 MB  [0,16)
    bf16_t* xb     = (bf16_t*)(ws + (16LL << 20));      // 8 MB   [16,24)
    bf16_t* qkv    = (bf16_t*)(ws + (24LL << 20));      // 24 MB  [24,48)
    bf16_t* vt     = (bf16_t*)(ws + (48LL << 20));      // 8 MB   [48,56)
    bf16_t* fpart  = (bf16_t*)(ws + (24LL << 20));      // 32 MB  [24,56) (aliases qkv/vt)
    bf16_t* scores = (bf16_t*)(ws + (56LL << 20));      // 8 MB   [56,64) (aliases h)
    bf16_t* p      = (bf16_t*)(ws + (72LL << 20));      // 8 MB   [72,80) (aliases h)
    bf16_t* h      = (bf16_t*)(ws + (56LL << 20));      // 32 MB  [56,88)
    bf16_t* attn   = (bf16_t*)(ws + (88LL << 20));      // 8 MB   [88,96)
    bf16_t* wqkvTA = (bf16_t*)(ws + (96LL << 20));      // 36 MB  [96,132)
    bf16_t* wf1TA  = (bf16_t*)(ws + (132LL << 20));     // 48 MB  [132,180)
    bf16_t* wf2TA  = (bf16_t*)(ws + (180LL << 20));     // 48 MB  [180,228)
    float*  qbiasA = (float*)(ws + (228LL << 20));      // 72 KB

    const size_t DD = 1024 * 1024;

    prep_kernel<<<21064, 256, 0, stream>>>(Wq, Wk, Wv, Wf1, Wf2, bq, bk, bv,
                                           ids, emb, wqkvTA, wf1TA, wf2TA, qbiasA, x, xb);

    for (int l = 0; l < 6; l++) {
        // fused QKV: [4096,1024] x [3072,1024]^T -> qkv [4096,3072]
        gemm8p<0><<<dim3(12, 16, 1), 512, 0, stream>>>(xb, 1024, wqkvTA + (size_t)l * 3 * DD, 1024,
                                                       qkv, 3072, qbiasA + l * 3072, 1024, 0, 0);
        // scores = Q K^T * 1/32  (bf16)
        gemm_db<3><<<dim3(8, 8, 4), 256, 0, stream>>>(qkv, 3072, 1024L * 3072,
                                                      qkv + 1024, 3072, 1024L * 3072,
                                                      scores, 1024, 1024L * 1024,
                                                      nullptr, 1024, 0.03125f);
        // softmax + V^T (merged)
        softvt_kernel<<<2048, 256, 0, stream>>>(scores, am, p, qkv, vt);
        // attn = P V  (via V^T as Bt)
        gemm_db<0><<<dim3(8, 8, 4), 256, 0, stream>>>(p, 1024, 1024L * 1024,
                                                      vt, 1024, 1024L * 1024,
                                                      attn, 1024, 1024L * 1024,
                                                      nullptr, 1024, 0.f);
        ln_kernel<<<4096, 256, 0, stream>>>(x, attn, g1 + l * 1024, be1 + l * 1024, x, xb);
        // FF1 with relu -> h [4096,4096]
        gemm8p<1><<<dim3(16, 16, 1), 512, 0, stream>>>(xb, 1024, wf1TA + (size_t)l * 4 * DD, 1024,
                                                       h, 4096, bf1 + l * 4096, 1024, 0, 0);
        // FF2 split-K=4 -> fpart
        gemm8p<0><<<dim3(4, 16, 4), 512, 0, stream>>>(h, 4096, wf2TA + (size_t)l * 4 * DD, 4096,
                                                      fpart, 1024, nullptr, 1024,
                                                      1024, 4096L * 1024);
        float* xo = (l == 5) ? (float*)d_out : x;
        ln4_kernel<<<4096, 256, 0, stream>>>(x, fpart, 4096L * 1024, bf2_ + l * 1024,
                                             g2 + l * 1024, be2 + l * 1024, xo, xb);
    }
    (void)in_sizes; (void)n_in; (void)out_size; (void)ws_size;
}

// Round 11
// 1175.197 us; speedup vs baseline: 1.1645x; 1.0379x over previous
//
#include <hip/hip_runtime.h>

typedef __bf16 bf16_t;
typedef __bf16 bf16x8 __attribute__((ext_vector_type(8)));
typedef float f32x4 __attribute__((ext_vector_type(4)));
typedef float f32x16 __attribute__((ext_vector_type(16)));
typedef unsigned short u16;

#define DEV static __device__ __forceinline__

DEV float bf2f(u16 u) { __bf16 h = __builtin_bit_cast(__bf16, u); return (float)h; }
DEV u16 f2bf(float f) { __bf16 h = (__bf16)f; return __builtin_bit_cast(u16, h); }

// async global->LDS, 16B per lane; lds base must be wave-uniform.
DEV void gll16(bf16_t* lds, const bf16_t* g) {
    __builtin_amdgcn_global_load_lds(
        (const __attribute__((address_space(1))) void*)g,
        (__attribute__((address_space(3))) void*)lds, 16, 0, 0);
}

#define WAITV(N) asm volatile("s_waitcnt vmcnt(" #N ")" ::: "memory")

// ---------------------------------------------------------------------------
// 256x256-tile GEMM, 8 waves (2M x 4N), BK=64, double-buffered 128KiB LDS,
// round-8 schedule, 32x32x16 MFMA. (unchanged from round 10)
// EPI: 0 = bf16 out (+f32 bias if non-null), 1 = bf16 out + bias + relu
// ---------------------------------------------------------------------------
template <int EPI>
__global__ __launch_bounds__(512, 1)
void gemm8p(const bf16_t* __restrict__ A, int lda,
            const bf16_t* __restrict__ Bt, int ldb,
            bf16_t* __restrict__ C, int ldc,
            const float* __restrict__ bias, int K,
            long kadv, long cadv)
{
    __shared__ bf16_t Asm[2 * 2 * 8192];   // [buf][half][128*64]
    __shared__ bf16_t Bsm[2 * 2 * 8192];
    const int tid = threadIdx.x, w = tid >> 6, l = tid & 63;
    const int z = blockIdx.z;
    A  += (size_t)z * kadv;
    Bt += (size_t)z * kadv;
    C  += (size_t)z * cadv;

    const int gx = gridDim.x;
    int lin = blockIdx.y * gx + blockIdx.x;
    const int nlin = gx * gridDim.y;
    lin = (lin & 7) * (nlin >> 3) + (lin >> 3);
    const size_t row0 = (size_t)(lin / gx) * 256;
    const size_t col0 = (size_t)(lin % gx) * 256;

    const int wr = w >> 2, wc = w & 3;
    const int bh = wc >> 1;
    const int browoff = (wc & 1) * 64;
    const int r32 = l & 31, hk = l >> 5, sw = l & 7;

    const int srow = w * 8 + (l >> 3);
    const int sslot8 = ((l & 7) ^ ((l >> 3) & 7)) * 8;
    const bf16_t* AgH0 = A  + (row0 + srow) * (size_t)lda + sslot8;
    const bf16_t* BgH0 = Bt + (col0 + srow) * (size_t)ldb + sslot8;
    const size_t a128 = (size_t)128 * lda, b128 = (size_t)128 * ldb;
    const size_t a64  = (size_t)64 * lda,  b64  = (size_t)64 * ldb;
    const int wlds = w * 512;

#define STAGE_PAIR(buf, tt, p)                                                 \
    do {                                                                       \
        const int koff = (tt) * 64;                                            \
        if ((p) == 0) {                                                        \
            gll16(Asm + ((buf)*2+0)*8192 + wlds,        AgH0 + koff);          \
            gll16(Asm + ((buf)*2+0)*8192 + 4096 + wlds, AgH0 + koff + a64);    \
        } else if ((p) == 1) {                                                 \
            gll16(Asm + ((buf)*2+1)*8192 + wlds,        AgH0 + a128 + koff);   \
            gll16(Asm + ((buf)*2+1)*8192 + 4096 + wlds, AgH0 + a128 + koff + a64); \
        } else if ((p) == 2) {                                                 \
            gll16(Bsm + ((buf)*2+0)*8192 + wlds,        BgH0 + koff);          \
            gll16(Bsm + ((buf)*2+0)*8192 + 4096 + wlds, BgH0 + koff + b64);    \
        } else {                                                               \
            gll16(Bsm + ((buf)*2+1)*8192 + wlds,        BgH0 + b128 + koff);   \
            gll16(Bsm + ((buf)*2+1)*8192 + 4096 + wlds, BgH0 + b128 + koff + b64); \
        }                                                                      \
    } while (0)

    f32x16 acc[4][2] = {};
    const int NT = K >> 6;

    STAGE_PAIR(0, 0, 0); STAGE_PAIR(0, 0, 1); STAGE_PAIR(0, 0, 2); STAGE_PAIR(0, 0, 3);
    if (NT > 1) { STAGE_PAIR(1, 1, 0); WAITV(2); } else { WAITV(0); }
    __builtin_amdgcn_sched_barrier(0);
    __builtin_amdgcn_s_barrier();

    for (int t = 0; t < NT; ++t) {
        const int cur = t & 1, nxt = cur ^ 1;
        const bool hasN1 = (t + 1 < NT), hasN2 = (t + 2 < NT);
        const bf16_t* Ab = Asm + (cur * 2 + wr) * 8192;
        const bf16_t* Bb = Bsm + (cur * 2 + bh) * 8192;

        bf16x8 bR[2][4], aR[2][4];
#pragma unroll
        for (int ni = 0; ni < 2; ni++)
#pragma unroll
            for (int ks = 0; ks < 4; ks++)
                bR[ni][ks] = *(const bf16x8*)&Bb[(browoff + ni * 32 + r32) * 64 + ((ks * 2 + hk) ^ sw) * 8];
#pragma unroll
        for (int mi = 0; mi < 2; mi++)
#pragma unroll
            for (int ks = 0; ks < 4; ks++)
                aR[mi][ks] = *(const bf16x8*)&Ab[(mi * 32 + r32) * 64 + ((ks * 2 + hk) ^ sw) * 8];
        if (hasN1) { STAGE_PAIR(nxt, t + 1, 1); STAGE_PAIR(nxt, t + 1, 2); }
        __builtin_amdgcn_s_setprio(1);
#pragma unroll
        for (int mi = 0; mi < 2; mi++)
#pragma unroll
            for (int ni = 0; ni < 2; ni++)
#pragma unroll
                for (int ks = 0; ks < 4; ks++)
                    acc[mi][ni] = __builtin_amdgcn_mfma_f32_32x32x16_bf16(aR[mi][ks], bR[ni][ks], acc[mi][ni], 0, 0, 0);
        __builtin_amdgcn_s_setprio(0);

        bf16x8 a2[2][4];
#pragma unroll
        for (int mi = 0; mi < 2; mi++)
#pragma unroll
            for (int ks = 0; ks < 4; ks++)
                a2[mi][ks] = *(const bf16x8*)&Ab[((2 + mi) * 32 + r32) * 64 + ((ks * 2 + hk) ^ sw) * 8];
        if (hasN1) STAGE_PAIR(nxt, t + 1, 3);
        __builtin_amdgcn_s_setprio(1);
#pragma unroll
        for (int mi = 0; mi < 2; mi++)
#pragma unroll
            for (int ni = 0; ni < 2; ni++)
#pragma unroll
                for (int ks = 0; ks < 4; ks++)
                    acc[2 + mi][ni] = __builtin_amdgcn_mfma_f32_32x32x16_bf16(a2[mi][ks], bR[ni][ks], acc[2 + mi][ni], 0, 0, 0);
        __builtin_amdgcn_s_setprio(0);

        __builtin_amdgcn_s_barrier();
        if (hasN2) STAGE_PAIR(cur, t + 2, 0);
        if (hasN1) {
            if (hasN2) { WAITV(2); } else { WAITV(0); }
            __builtin_amdgcn_sched_barrier(0);
        }
        __builtin_amdgcn_s_barrier();
    }
#undef STAGE_PAIR

#pragma unroll
    for (int ni = 0; ni < 2; ni++) {
        size_t c = col0 + wc * 64 + ni * 32 + r32;
        float bv = bias ? bias[c] : 0.f;
#pragma unroll
        for (int mi = 0; mi < 4; mi++) {
            size_t rb = row0 + wr * 128 + mi * 32 + hk * 4;
#pragma unroll
            for (int reg = 0; reg < 16; reg++) {
                size_t r = rb + (reg & 3) + 8 * (reg >> 2);
                float v = acc[mi][ni][reg] + bv;
                if (EPI == 1) v = fmaxf(v, 0.f);
                C[r * ldc + c] = (bf16_t)v;
            }
        }
    }
}

// ---------------------------------------------------------------------------
// 128x128-tile GEMM, 4 waves, BK=64, dbuf LDS, 32x32x16 MFMA (unchanged).
// EPI: 0 bf16+bias, 1 +relu, 2 f32*scale, 3 bf16*scale
// ---------------------------------------------------------------------------
template <int EPI>
__global__ __launch_bounds__(256)
void gemm_db(const bf16_t* __restrict__ A, int lda, long sA,
             const bf16_t* __restrict__ Bt, int ldb, long sB,
             void* __restrict__ Cv, int ldc, long sC,
             const float* __restrict__ bias, int K, float scale)
{
    __shared__ bf16_t Asm[2][128 * 64];
    __shared__ bf16_t Bsm[2][128 * 64];
    const int tid = threadIdx.x, w = tid >> 6, l = tid & 63;
    const int bz = blockIdx.z;

    const int gx = gridDim.x;
    int lin = blockIdx.y * gx + blockIdx.x;
    const int nlin = gx * gridDim.y;
    lin = (lin & 7) * (nlin >> 3) + (lin >> 3);
    const size_t row0 = (size_t)(lin / gx) * 128;
    const size_t col0 = (size_t)(lin % gx) * 128;

    A  += (size_t)bz * sA;
    Bt += (size_t)bz * sB;

    const int lr = l >> 3;
    const int sl = (l & 7) ^ lr;
    const bf16_t* Ag = A  + (row0 + (size_t)(w * 32) + lr) * lda + sl * 8;
    const bf16_t* Bg = Bt + (col0 + (size_t)(w * 32) + lr) * ldb + sl * 8;
    const int wlds = (w * 32) * 64;

#define STA(buf, tt)                                                           \
    do { const int ko = (tt) * 64;                                             \
        _Pragma("unroll")                                                      \
        for (int c = 0; c < 4; c++)                                            \
            gll16(&Asm[buf][wlds + c * 8 * 64], Ag + (size_t)(c * 8) * lda + ko); \
    } while (0)
#define STB(buf, tt)                                                           \
    do { const int ko = (tt) * 64;                                             \
        _Pragma("unroll")                                                      \
        for (int c = 0; c < 4; c++)                                            \
            gll16(&Bsm[buf][wlds + c * 8 * 64], Bg + (size_t)(c * 8) * ldb + ko); \
    } while (0)

    const int wm = (w >> 1) * 64, wn = (w & 1) * 64;
    const int r32 = l & 31, hk = l >> 5, sw = l & 7;
    f32x16 acc[2][2] = {};
    const int NT = K >> 6;

    STA(0, 0); STB(0, 0);
    if (NT > 1) { STA(1, 1); WAITV(4); } else { WAITV(0); }
    __builtin_amdgcn_sched_barrier(0);
    __builtin_amdgcn_s_barrier();

    for (int t = 0; t < NT; ++t) {
        const int cur = t & 1, nxt = cur ^ 1;
        const bool hasN1 = (t + 1 < NT), hasN2 = (t + 2 < NT);

        bf16x8 a0[2][2], b0[2][2];
#pragma unroll
        for (int i = 0; i < 2; i++)
#pragma unroll
            for (int ks = 0; ks < 2; ks++) {
                a0[i][ks] = *(const bf16x8*)&Asm[cur][(wm + i * 32 + r32) * 64 + ((ks * 2 + hk) ^ sw) * 8];
                b0[i][ks] = *(const bf16x8*)&Bsm[cur][(wn + i * 32 + r32) * 64 + ((ks * 2 + hk) ^ sw) * 8];
            }
        if (hasN1) STB(nxt, t + 1);
        __builtin_amdgcn_s_setprio(1);
#pragma unroll
        for (int mi = 0; mi < 2; mi++)
#pragma unroll
            for (int ni = 0; ni < 2; ni++)
#pragma unroll
                for (int ks = 0; ks < 2; ks++)
                    acc[mi][ni] = __builtin_amdgcn_mfma_f32_32x32x16_bf16(a0[mi][ks], b0[ni][ks], acc[mi][ni], 0, 0, 0);
        __builtin_amdgcn_s_setprio(0);

        bf16x8 a1[2][2], b1[2][2];
#pragma unroll
        for (int i = 0; i < 2; i++)
#pragma unroll
            for (int ks = 0; ks < 2; ks++) {
                a1[i][ks] = *(const bf16x8*)&Asm[cur][(wm + i * 32 + r32) * 64 + (((2 + ks) * 2 + hk) ^ sw) * 8];
                b1[i][ks] = *(const bf16x8*)&Bsm[cur][(wn + i * 32 + r32) * 64 + (((2 + ks) * 2 + hk) ^ sw) * 8];
            }
        __builtin_amdgcn_s_setprio(1);
#pragma unroll
        for (int mi = 0; mi < 2; mi++)
#pragma unroll
            for (int ni = 0; ni < 2; ni++)
#pragma unroll
                for (int ks = 0; ks < 2; ks++)
                    acc[mi][ni] = __builtin_amdgcn_mfma_f32_32x32x16_bf16(a1[mi][ks], b1[ni][ks], acc[mi][ni], 0, 0, 0);
        __builtin_amdgcn_s_setprio(0);

        __builtin_amdgcn_s_barrier();
        if (hasN2) STA(cur, t + 2);
        if (hasN1) {
            if (hasN2) { WAITV(4); } else { WAITV(0); }
            __builtin_amdgcn_sched_barrier(0);
        }
        __builtin_amdgcn_s_barrier();
    }
#undef STA
#undef STB

#pragma unroll
    for (int ni = 0; ni < 2; ni++) {
        size_t c = col0 + wn + ni * 32 + r32;
        float bv = (EPI == 0 || EPI == 1) ? (bias ? bias[c] : 0.f) : 0.f;
#pragma unroll
        for (int mi = 0; mi < 2; mi++) {
            size_t rb = row0 + wm + mi * 32 + hk * 4;
#pragma unroll
            for (int reg = 0; reg < 16; reg++) {
                size_t r = rb + (reg & 3) + 8 * (reg >> 2);
                float v = acc[mi][ni][reg];
                if (EPI == 2) {
                    ((float*)Cv + (size_t)bz * sC)[r * ldc + c] = v * scale;
                } else if (EPI == 3) {
                    ((bf16_t*)Cv + (size_t)bz * sC)[r * ldc + c] = (bf16_t)(v * scale);
                } else {
                    v += bv;
                    if (EPI == 1) v = fmaxf(v, 0.f);
                    ((bf16_t*)Cv + (size_t)bz * sC)[r * ldc + c] = (bf16_t)v;
                }
            }
        }
    }
}

// ---------------------------------------------------------------------------
// one-shot preprocessing. Transposes use 256-row x 64-col input strips
// (4 sub-tiles of 64x64 buffered in 32KB LDS, proven XOR-group layout);
// write phase emits 512B contiguous per output row (32 lanes x 16B).
// Grid regions: [0,4224) transpose; [4224,4296) bias; [4296,8392) embed.
// ---------------------------------------------------------------------------
__global__ __launch_bounds__(256)
void prep_kernel(const float* __restrict__ Wq, const float* __restrict__ Wk,
                 const float* __restrict__ Wv, const float* __restrict__ Wf1,
                 const float* __restrict__ Wf2,
                 const float* __restrict__ bq, const float* __restrict__ bk,
                 const float* __restrict__ bv,
                 const int* __restrict__ ids, const float* __restrict__ emb,
                 bf16_t* __restrict__ wqkvTA, bf16_t* __restrict__ wf1TA,
                 bf16_t* __restrict__ wf2TA, float* __restrict__ qbiasA,
                 bf16_t* __restrict__ xb)
{
    __shared__ bf16_t tls[4][64 * 64];   // 32 KB
    const size_t DD = 1024 * 1024;
    int id = blockIdx.x;
    if (id < 4224) {
        const float* src; bf16_t* dst; int ldin, ldout, bx, by;
        if (id < 1152) {
            // QKV: [1024][1024], 4 row-strips x 16 col-tiles = 64 tiles/matrix
            int layer = id / 192, r = id % 192, which = r >> 6, t = r & 63;
            src = (which == 0 ? Wq : which == 1 ? Wk : Wv) + (size_t)layer * DD;
            dst = wqkvTA + (size_t)layer * 3 * DD + (size_t)which * DD;
            ldin = 1024; ldout = 1024; bx = (t & 15) * 64; by = (t >> 4) * 256;
        } else if (id < 2688) {
            // Wf1: [1024][4096], 4 strips x 64 col-tiles = 256/layer
            int i = id - 1152, layer = i >> 8, t = i & 255;
            src = Wf1 + (size_t)layer * 4 * DD; dst = wf1TA + (size_t)layer * 4 * DD;
            ldin = 4096; ldout = 1024; bx = (t & 63) * 64; by = (t >> 6) * 256;
        } else {
            // Wf2: [4096][1024], 16 strips x 16 col-tiles = 256/layer
            int i = id - 2688, layer = i >> 8, t = i & 255;
            src = Wf2 + (size_t)layer * 4 * DD; dst = wf2TA + (size_t)layer * 4 * DD;
            ldin = 1024; ldout = 4096; bx = (t & 15) * 64; by = (t >> 4) * 256;
        }
        const int tid = threadIdx.x;
        const int cg = tid & 15, ri = tid >> 4;
#pragma unroll
        for (int sub = 0; sub < 4; sub++) {
#pragma unroll
            for (int k = 0; k < 4; k++) {
                int r = ri + k * 16;
                float4 v = *(const float4*)&src[(size_t)(by + sub * 64 + r) * ldin + bx + cg * 4];
                ushort4 o = {f2bf(v.x), f2bf(v.y), f2bf(v.z), f2bf(v.w)};
                int g = cg ^ ((r >> 2) & 15);
                *(ushort4*)&tls[sub][r * 64 + g * 4] = o;
            }
        }
        __syncthreads();
        // write: 8 passes; thread -> out row i = p*8+(tid>>5), 16B chunk c = tid&31
        const int c = tid & 31, sub = c >> 3, j = c & 7;
#pragma unroll
        for (int p = 0; p < 8; p++) {
            int i = p * 8 + (tid >> 5);
            u16 vals[8];
#pragma unroll
            for (int m = 0; m < 8; m++) {
                int rr = j * 8 + m;
                int gg = ((i >> 2) ^ (rr >> 2)) & 15;
                vals[m] = __builtin_bit_cast(u16, tls[sub][rr * 64 + gg * 4 + (i & 3)]);
            }
            uint4 ov;
            ov.x = (unsigned)vals[0] | ((unsigned)vals[1] << 16);
            ov.y = (unsigned)vals[2] | ((unsigned)vals[3] << 16);
            ov.z = (unsigned)vals[4] | ((unsigned)vals[5] << 16);
            ov.w = (unsigned)vals[6] | ((unsigned)vals[7] << 16);
            *(uint4*)&dst[(size_t)(bx + i) * ldout + by + c * 8] = ov;
        }
        return;
    }
    id -= 4224;
    if (id < 72) {
        int i = id * 256 + threadIdx.x;
        int lyr = i / 3072, j = i - lyr * 3072;
        qbiasA[i] = (j < 1024) ? bq[lyr * 1024 + j]
                  : (j < 2048) ? bk[lyr * 1024 + j - 1024]
                               : bv[lyr * 1024 + j - 2048];
        return;
    }
    id -= 72;
    const int row = id;
    const int s = row & 1023;
    const int eid = ids[row];
    const float* er = emb + (size_t)eid * 1024;
    bf16_t* br = xb + (size_t)row * 1024;
#pragma unroll
    for (int k = 0; k < 2; k++) {
        int i = threadIdx.x + 256 * k;
        int d = 2 * i;
        float dv = expf((float)d * -0.008994473019508f);
        float ph = (float)s * dv;
        float sv, cv;
        sincosf(ph, &sv, &cv);
        float2 ev = *(const float2*)&er[d];
        ushort2 bo = {f2bf(ev.x + sv), f2bf(ev.y + cv)};
        *(ushort2*)&br[d] = bo;
    }
}

// ---------------------------------------------------------------------------
// merged masked-softmax over bf16 scores (blocks 0..1023) + V^T transpose
// (blocks 1024..2047).
// ---------------------------------------------------------------------------
__global__ __launch_bounds__(256)
void softvt_kernel(const bf16_t* __restrict__ sc, const int* __restrict__ amask,
                   bf16_t* __restrict__ p, const bf16_t* __restrict__ qkv,
                   bf16_t* __restrict__ vt)
{
    __shared__ bf16_t tls[64][72];
    int bid = blockIdx.x;
    if (bid < 1024) {
        const int row = bid * 4 + (threadIdx.x >> 6);
        const int l = threadIdx.x & 63;
        const int b = row >> 10;
        const bf16_t* s = sc + (size_t)row * 1024;
        const int* m = amask + (size_t)b * 1024;
        float v[16];
        float mx = -3.0e38f;
#pragma unroll
        for (int i = 0; i < 4; i++) {
            int c = 4 * l + 256 * i;
            ushort4 su = *(const ushort4*)&s[c];
            int4 mv = *(const int4*)&m[c];
            v[4 * i + 0] = mv.x ? bf2f(su.x) : -1e9f;
            v[4 * i + 1] = mv.y ? bf2f(su.y) : -1e9f;
            v[4 * i + 2] = mv.z ? bf2f(su.z) : -1e9f;
            v[4 * i + 3] = mv.w ? bf2f(su.w) : -1e9f;
            mx = fmaxf(mx, fmaxf(fmaxf(v[4 * i], v[4 * i + 1]), fmaxf(v[4 * i + 2], v[4 * i + 3])));
        }
#pragma unroll
        for (int o = 32; o; o >>= 1) mx = fmaxf(mx, __shfl_xor(mx, o, 64));
        float sum = 0.f;
#pragma unroll
        for (int i = 0; i < 16; i++) { v[i] = __expf(v[i] - mx); sum += v[i]; }
#pragma unroll
        for (int o = 32; o; o >>= 1) sum += __shfl_xor(sum, o, 64);
        float inv = 1.0f / sum;
#pragma unroll
        for (int i = 0; i < 4; i++) {
            int c = 4 * l + 256 * i;
            ushort4 st;
            st.x = f2bf(v[4 * i + 0] * inv);
            st.y = f2bf(v[4 * i + 1] * inv);
            st.z = f2bf(v[4 * i + 2] * inv);
            st.w = f2bf(v[4 * i + 3] * inv);
            *(ushort4*)&p[(size_t)row * 1024 + c] = st;
        }
        return;
    }
    bid -= 1024;
    const int z = bid >> 8, t = bid & 255;
    const bf16_t* in = qkv + 2048 + (size_t)z * 1024 * 3072;
    bf16_t* out = vt + (size_t)z * 1024 * 1024;
    const int bx = (t & 15) * 64, by = (t >> 4) * 64;
    const int tid = threadIdx.x;
    const int cj = (tid & 15) * 4, ri = tid >> 4;
#pragma unroll
    for (int k = 0; k < 4; k++) {
        int r = ri + k * 16;
        *(ushort4*)&tls[r][cj] = *(const ushort4*)&in[(size_t)(by + r) * 3072 + bx + cj];
    }
    __syncthreads();
#pragma unroll
    for (int k = 0; k < 4; k++) {
        int i2 = ri + k * 16;
        ushort4 o;
        o.x = __builtin_bit_cast(u16, tls[cj + 0][i2]);
        o.y = __builtin_bit_cast(u16, tls[cj + 1][i2]);
        o.z = __builtin_bit_cast(u16, tls[cj + 2][i2]);
        o.w = __builtin_bit_cast(u16, tls[cj + 3][i2]);
        *(ushort4*)&out[(size_t)(bx + i2) * 1024 + by + cj] = o;
    }
}

// ---------------------------------------------------------------------------
// residual + LayerNorm, bf16 residual stream: t = xin + add; out = LN(t)*g+beta
// ---------------------------------------------------------------------------
__global__ __launch_bounds__(256)
void ln_kernel(const bf16_t* __restrict__ xin, const bf16_t* __restrict__ add,
               const float* __restrict__ g, const float* __restrict__ beta,
               bf16_t* __restrict__ out)
{
    __shared__ float red[8];
    const int row = blockIdx.x;
    const int t = threadIdx.x;
    const size_t base = (size_t)row * 1024 + t * 4;
    ushort4 xu = *(const ushort4*)&xin[base];
    ushort4 au = *(const ushort4*)&add[base];
    float tv[4];
    tv[0] = bf2f(xu.x) + bf2f(au.x);
    tv[1] = bf2f(xu.y) + bf2f(au.y);
    tv[2] = bf2f(xu.z) + bf2f(au.z);
    tv[3] = bf2f(xu.w) + bf2f(au.w);
    float s = tv[0] + tv[1] + tv[2] + tv[3];
    float s2 = tv[0] * tv[0] + tv[1] * tv[1] + tv[2] * tv[2] + tv[3] * tv[3];
#pragma unroll
    for (int o = 32; o; o >>= 1) { s += __shfl_xor(s, o, 64); s2 += __shfl_xor(s2, o, 64); }
    if ((t & 63) == 0) { red[t >> 6] = s; red[4 + (t >> 6)] = s2; }
    __syncthreads();
    s = red[0] + red[1] + red[2] + red[3];
    s2 = red[4] + red[5] + red[6] + red[7];
    const float mu = s * (1.f / 1024.f);
    const float var = s2 * (1.f / 1024.f) - mu * mu;
    const float rs = rsqrtf(var + 1e-5f);
    float4 gu = *(const float4*)&g[t * 4];
    float4 bu = *(const float4*)&beta[t * 4];
    ushort4 ob;
    ob.x = f2bf((tv[0] - mu) * rs * gu.x + bu.x);
    ob.y = f2bf((tv[1] - mu) * rs * gu.y + bu.y);
    ob.z = f2bf((tv[2] - mu) * rs * gu.z + bu.z);
    ob.w = f2bf((tv[3] - mu) * rs * gu.w + bu.w);
    *(ushort4*)&out[base] = ob;
}

// ---------------------------------------------------------------------------
// residual + 4-plane-sum + bias + LayerNorm (split-K FF2), bf16 residual.
// F32OUT: 1 -> write f32 (final d_out), 0 -> write bf16 residual.
// ---------------------------------------------------------------------------
template <int F32OUT>
__global__ __launch_bounds__(256)
void ln4_kernel(const bf16_t* __restrict__ xin, const bf16_t* __restrict__ p,
                long pstride, const float* __restrict__ fbias,
                const float* __restrict__ g, const float* __restrict__ beta,
                void* __restrict__ outv)
{
    __shared__ float red[8];
    const int row = blockIdx.x;
    const int t = threadIdx.x;
    const size_t base = (size_t)row * 1024 + t * 4;
    ushort4 xu = *(const ushort4*)&xin[base];
    float4 bb = *(const float4*)&fbias[t * 4];
    float tv[4] = {bf2f(xu.x) + bb.x, bf2f(xu.y) + bb.y,
                   bf2f(xu.z) + bb.z, bf2f(xu.w) + bb.w};
#pragma unroll
    for (int z = 0; z < 4; z++) {
        ushort4 au = *(const ushort4*)&p[(size_t)z * pstride + base];
        tv[0] += bf2f(au.x); tv[1] += bf2f(au.y);
        tv[2] += bf2f(au.z); tv[3] += bf2f(au.w);
    }
    float s = tv[0] + tv[1] + tv[2] + tv[3];
    float s2 = tv[0] * tv[0] + tv[1] * tv[1] + tv[2] * tv[2] + tv[3] * tv[3];
#pragma unroll
    for (int o = 32; o; o >>= 1) { s += __shfl_xor(s, o, 64); s2 += __shfl_xor(s2, o, 64); }
    if ((t & 63) == 0) { red[t >> 6] = s; red[4 + (t >> 6)] = s2; }
    __syncthreads();
    s = red[0] + red[1] + red[2] + red[3];
    s2 = red[4] + red[5] + red[6] + red[7];
    const float mu = s * (1.f / 1024.f);
    const float var = s2 * (1.f / 1024.f) - mu * mu;
    const float rs = rsqrtf(var + 1e-5f);
    float4 gu = *(const float4*)&g[t * 4];
    float4 bu = *(const float4*)&beta[t * 4];
    float y0 = (tv[0] - mu) * rs * gu.x + bu.x;
    float y1 = (tv[1] - mu) * rs * gu.y + bu.y;
    float y2 = (tv[2] - mu) * rs * gu.z + bu.z;
    float y3 = (tv[3] - mu) * rs * gu.w + bu.w;
    if (F32OUT) {
        float4 yo = {y0, y1, y2, y3};
        *(float4*)&((float*)outv)[base] = yo;
    } else {
        ushort4 ob = {f2bf(y0), f2bf(y1), f2bf(y2), f2bf(y3)};
        *(ushort4*)&((bf16_t*)outv)[base] = ob;
    }
}

// ---------------------------------------------------------------------------

extern "C" void kernel_launch(void* const* d_in, const int* in_sizes, int n_in,
                              void* d_out, int out_size, void* d_ws, size_t ws_size,
                              hipStream_t stream)
{
    const int*   ids = (const int*)d_in[0];
    const int*   am  = (const int*)d_in[1];
    const float* emb = (const float*)d_in[2];
    const float* Wq  = (const float*)d_in[3];
    const float* Wk  = (const float*)d_in[4];
    const float* Wv  = (const float*)d_in[5];
    const float* bq  = (const float*)d_in[6];
    const float* bk  = (const float*)d_in[7];
    const float* bv  = (const float*)d_in[8];
    const float* g1  = (const float*)d_in[9];
    const float* be1 = (const float*)d_in[10];
    const float* Wf1 = (const float*)d_in[11];
    const float* bf1 = (const float*)d_in[12];
    const float* Wf2 = (const float*)d_in[13];
    const float* bf2_ = (const float*)d_in[14];
    const float* g2  = (const float*)d_in[15];
    const float* be2 = (const float*)d_in[16];

    char* ws = (char*)d_ws;
    bf16_t* xb     = (bf16_t*)(ws + (16LL << 20));      // 8 MB   [16,24)  residual (bf16)
    bf16_t* qkv    = (bf16_t*)(ws + (24LL << 20));      // 24 MB  [24,48)
    bf16_t* vt     = (bf16_t*)(ws + (48LL << 20));      // 8 MB   [48,56)
    bf16_t* fpart  = (bf16_t*)(ws + (24LL << 20));      // 32 MB  [24,56) (aliases qkv/vt)
    bf16_t* scores = (bf16_t*)(ws + (56LL << 20));      // 8 MB   [56,64) (aliases h)
    bf16_t* p      = (bf16_t*)(ws + (72LL << 20));      // 8 MB   [72,80) (aliases h)
    bf16_t* h      = (bf16_t*)(ws + (56LL << 20));      // 32 MB  [56,88)
    bf16_t* attn   = (bf16_t*)(ws + (88LL << 20));      // 8 MB   [88,96)
    bf16_t* wqkvTA = (bf16_t*)(ws + (96LL << 20));      // 36 MB  [96,132)
    bf16_t* wf1TA  = (bf16_t*)(ws + (132LL << 20));     // 48 MB  [132,180)
    bf16_t* wf2TA  = (bf16_t*)(ws + (180LL << 20));     // 48 MB  [180,228)
    float*  qbiasA = (float*)(ws + (228LL << 20));      // 72 KB

    const size_t DD = 1024 * 1024;

    prep_kernel<<<8392, 256, 0, stream>>>(Wq, Wk, Wv, Wf1, Wf2, bq, bk, bv,
                                          ids, emb, wqkvTA, wf1TA, wf2TA, qbiasA, xb);

    for (int l = 0; l < 6; l++) {
        // fused QKV: [4096,1024] x [3072,1024]^T -> qkv [4096,3072]
        gemm8p<0><<<dim3(12, 16, 1), 512, 0, stream>>>(xb, 1024, wqkvTA + (size_t)l * 3 * DD, 1024,
                                                       qkv, 3072, qbiasA + l * 3072, 1024, 0, 0);
        // scores = Q K^T * 1/32  (bf16)
        gemm_db<3><<<dim3(8, 8, 4), 256, 0, stream>>>(qkv, 3072, 1024L * 3072,
                                                      qkv + 1024, 3072, 1024L * 3072,
                                                      scores, 1024, 1024L * 1024,
                                                      nullptr, 1024, 0.03125f);
        // softmax + V^T (merged)
        softvt_kernel<<<2048, 256, 0, stream>>>(scores, am, p, qkv, vt);
        // attn = P V  (via V^T as Bt)
        gemm_db<0><<<dim3(8, 8, 4), 256, 0, stream>>>(p, 1024, 1024L * 1024,
                                                      vt, 1024, 1024L * 1024,
                                                      attn, 1024, 1024L * 1024,
                                                      nullptr, 1024, 0.f);
        ln_kernel<<<4096, 256, 0, stream>>>(xb, attn, g1 + l * 1024, be1 + l * 1024, xb);
        // FF1 with relu -> h [4096,4096]
        gemm8p<1><<<dim3(16, 16, 1), 512, 0, stream>>>(xb, 1024, wf1TA + (size_t)l * 4 * DD, 1024,
                                                       h, 4096, bf1 + l * 4096, 1024, 0, 0);
        // FF2 split-K=4 -> fpart
        gemm8p<0><<<dim3(4, 16, 4), 512, 0, stream>>>(h, 4096, wf2TA + (size_t)l * 4 * DD, 4096,
                                                      fpart, 1024, nullptr, 1024,
                                                      1024, 4096L * 1024);
        if (l == 5)
            ln4_kernel<1><<<4096, 256, 0, stream>>>(xb, fpart, 4096L * 1024, bf2_ + l * 1024,
                                                    g2 + l * 1024, be2 + l * 1024, d_out);
        else
            ln4_kernel<0><<<4096, 256, 0, stream>>>(xb, fpart, 4096L * 1024, bf2_ + l * 1024,
                                                    g2 + l * 1024, be2 + l * 1024, xb);
    }
    (void)in_sizes; (void)n_in; (void)out_size; (void)ws_size;
}